// Round 9
// baseline (305.471 us; speedup 1.0000x reference)
//
#include <hip/hip_runtime.h>

typedef __bf16 bf16;
typedef __attribute__((ext_vector_type(4))) __bf16 bf16x4;
typedef __attribute__((ext_vector_type(8))) __bf16 bf16x8;
typedef __attribute__((ext_vector_type(4))) float f32x4;

__device__ __forceinline__ void gload_lds16(const void* g, void* l) {
  __builtin_amdgcn_global_load_lds(
      (const __attribute__((address_space(1))) unsigned int*)(unsigned long long)g,
      (__attribute__((address_space(3))) unsigned int*)(unsigned long long)l,
      16, 0, 0);
}

// ---------------- cast fp32 -> bf16 (x4 vectorized) -- weights only ----------------
__global__ void cast_f32_bf16(const float* __restrict__ in, bf16* __restrict__ out, int n4) {
  int i = blockIdx.x * blockDim.x + threadIdx.x;
  if (i >= n4) return;
  float4 v = reinterpret_cast<const float4*>(in)[i];
  bf16x4 o;
  o[0] = (bf16)v.x; o[1] = (bf16)v.y; o[2] = (bf16)v.z; o[3] = (bf16)v.w;
  reinterpret_cast<bf16x4*>(out)[i] = o;
}

// ------- transpose+cast: V (rows x cols, f32) -> VT (cols x rows, bf16), batched -------
__global__ void transpose_cast(const float* __restrict__ V, bf16* __restrict__ VT,
                               int rows, int cols) {
  __shared__ bf16 tile[64][65];
  const int b = blockIdx.z;
  const float* Vb = V + (long)b * rows * cols;
  bf16* VTb = VT + (long)b * rows * cols;
  const int d0 = blockIdx.x * 64;
  const int k0 = blockIdx.y * 64;
  const int t = threadIdx.x;
  const int r = t >> 4;
  const int c4 = (t & 15) * 4;
#pragma unroll
  for (int p = 0; p < 4; ++p) {
    float4 v = *reinterpret_cast<const float4*>(&Vb[(long)(k0 + p * 16 + r) * cols + d0 + c4]);
    tile[p * 16 + r][c4 + 0] = (bf16)v.x;
    tile[p * 16 + r][c4 + 1] = (bf16)v.y;
    tile[p * 16 + r][c4 + 2] = (bf16)v.z;
    tile[p * 16 + r][c4 + 3] = (bf16)v.w;
  }
  __syncthreads();
#pragma unroll
  for (int p = 0; p < 4; ++p) {
    const int dd = p * 16 + r;
    bf16x4 o;
    o[0] = tile[c4 + 0][dd];
    o[1] = tile[c4 + 1][dd];
    o[2] = tile[c4 + 2][dd];
    o[3] = tile[c4 + 3][dd];
    *reinterpret_cast<bf16x4*>(&VTb[(long)(d0 + dd) * rows + k0 + c4]) = o;
  }
}

// ---------------- in-place row softmax, row length 2048, bf16 ----------------
__global__ void softmax_rows(bf16* __restrict__ S) {
  const long row = blockIdx.x;
  bf16* p = S + row * 2048;
  const int t = threadIdx.x;
  const int wid = t >> 6;
  const int lane = t & 63;
  bf16x8 v = *reinterpret_cast<bf16x8*>(p + t * 8);
  float f[8];
  float m = -3.0e38f;
#pragma unroll
  for (int j = 0; j < 8; ++j) { f[j] = (float)v[j]; m = fmaxf(m, f[j]); }
#pragma unroll
  for (int off = 32; off >= 1; off >>= 1) m = fmaxf(m, __shfl_xor(m, off));
  __shared__ float redm[4], reds[4];
  if (lane == 0) redm[wid] = m;
  __syncthreads();
  m = fmaxf(fmaxf(redm[0], redm[1]), fmaxf(redm[2], redm[3]));
  float s = 0.f;
#pragma unroll
  for (int j = 0; j < 8; ++j) { f[j] = __expf(f[j] - m); s += f[j]; }
#pragma unroll
  for (int off = 32; off >= 1; off >>= 1) s += __shfl_xor(s, off);
  if (lane == 0) reds[wid] = s;
  __syncthreads();
  s = reds[0] + reds[1] + reds[2] + reds[3];
  const float inv = 1.0f / s;
  bf16x8 o;
#pragma unroll
  for (int j = 0; j < 8; ++j) o[j] = (bf16)(f[j] * inv);
  *reinterpret_cast<bf16x8*>(p + t * 8) = o;
}

// ---------------- B^T GEMM, 256x256 tile, BK=64, 8-phase (R2 core, best measured) ------
// MODE 1: bf16 out * (1/scale); MODE 2: f32 out.

#define BARRIER __builtin_amdgcn_s_barrier()
#define LGKM0                                              \
  do {                                                     \
    asm volatile("s_waitcnt lgkmcnt(0)" ::: "memory");     \
    __builtin_amdgcn_sched_barrier(0);                     \
  } while (0)
#define VM0                                                \
  do {                                                     \
    asm volatile("s_waitcnt vmcnt(0)" ::: "memory");       \
    __builtin_amdgcn_sched_barrier(0);                     \
  } while (0)

#define STAGE_A(buf, ko)                                        \
  {                                                             \
    bf16* l_ = ldsd + (buf) * 32768;                            \
    const bf16* g_ = gA + (ko);                                 \
    gload_lds16(g_, l_);                                        \
    gload_lds16(g_ + rK64, l_ + 4096);                          \
    gload_lds16(g_ + rK128, l_ + 8192);                         \
    gload_lds16(g_ + rK128 + rK64, l_ + 12288);                 \
  }
#define STAGE_B(buf, ko)                                        \
  {                                                             \
    bf16* l_ = ldsd + (buf) * 32768 + 16384;                    \
    const bf16* g_ = gB + (ko);                                 \
    gload_lds16(g_, l_);                                        \
    gload_lds16(g_ + rK64, l_ + 4096);                          \
    gload_lds16(g_ + rK128, l_ + 8192);                         \
    gload_lds16(g_ + rK128 + rK64, l_ + 12288);                 \
  }

#define LOADA(buf, mq)                                                        \
  {                                                                           \
    const bf16* p_ = aBase + (buf) * 32768 + (mq) * 4096;                     \
    _Pragma("unroll") for (int m_ = 0; m_ < 4; ++m_) {                        \
      a[m_][0] = *reinterpret_cast<const bf16x8*>(p_ + m_ * 1024 + pk0);      \
      a[m_][1] = *reinterpret_cast<const bf16x8*>(p_ + m_ * 1024 + pk1);      \
    }                                                                         \
  }
#define LOADB(buf, nq)                                                        \
  {                                                                           \
    const bf16* p_ = bBase + (buf) * 32768 + (nq) * 2048;                     \
    _Pragma("unroll") for (int n_ = 0; n_ < 2; ++n_) {                        \
      b[(nq) * 2 + n_][0] = *reinterpret_cast<const bf16x8*>(p_ + n_ * 1024 + pk0); \
      b[(nq) * 2 + n_][1] = *reinterpret_cast<const bf16x8*>(p_ + n_ * 1024 + pk1); \
    }                                                                         \
  }

#define MFMAQ(mq, nq)                                                         \
  _Pragma("unroll") for (int m_ = 0; m_ < 4; ++m_)                            \
  _Pragma("unroll") for (int n_ = 0; n_ < 2; ++n_)                            \
  _Pragma("unroll") for (int ks_ = 0; ks_ < 2; ++ks_)                         \
      acc[(mq) * 4 + m_][(nq) * 2 + n_] =                                     \
          __builtin_amdgcn_mfma_f32_16x16x32_bf16(                            \
              a[m_][ks_], b[(nq) * 2 + n_][ks_],                              \
              acc[(mq) * 4 + m_][(nq) * 2 + n_], 0, 0, 0);

template <int MODE>
__global__ __launch_bounds__(512, 2)
void gemm_bt(const bf16* __restrict__ A, const bf16* __restrict__ Bm,
             void* __restrict__ Cvoid, const int* __restrict__ scale_ptr,
             int N, int K, long sA, long sB, long sC) {
  __shared__ bf16 lds[2][2][2][128][64];  // [buf][opA/B][half][row][64k] = 128 KiB
  const int t = threadIdx.x;
  const int lane = t & 63;
  const int wid = t >> 6;   // 0..7
  const int wm = wid >> 2;  // 0..1
  const int wn = wid & 3;   // 0..3

  const int gx = gridDim.x, gy = gridDim.y;
  const int nwg = gx * gy * gridDim.z;
  int id = blockIdx.x + gx * (blockIdx.y + gy * blockIdx.z);
  {
    const int cpx = nwg >> 3;
    id = (id & 7) * cpx + (id >> 3);
  }
  const int bx = id % gx;
  const int by = (id / gx) % gy;
  const int bz = id / (gx * gy);

  const bf16* Ab = A + (long)bz * sA;
  const bf16* Bb = Bm + (long)bz * sB;
  const int tile_m = by * 256;
  const int tile_n = bx * 256;

  const int srow = t >> 3;
  const int skc = t & 7;
  const int soff = ((skc ^ (srow & 7)) << 3);
  const bf16* gA = Ab + (long)(tile_m + srow) * K + soff;
  const bf16* gB = Bb + (long)(tile_n + srow) * K + soff;
  const long rK64 = (long)K << 6;    // +64 rows
  const long rK128 = (long)K << 7;   // +128 rows
  bf16* const ldsd = &lds[0][0][0][0][0] + wid * 512;

  const int frow = lane & 15;
  const int pk0 = (((lane >> 4) ^ (lane & 7))) << 3;
  const int pk1 = (((4 | (lane >> 4)) ^ (lane & 7))) << 3;
  const bf16* aBase = &lds[0][0][wm][frow][0];
  const bf16* bBase = &lds[0][1][wn >> 1][(wn & 1) * 64 + frow][0];

  bf16x8 a[4][2], b[4][2];
  f32x4 acc[8][4] = {};

  STAGE_A(0, 0)
  STAGE_B(0, 0)
  VM0;
  BARRIER;

  const int NK = K >> 6;
  int c = 0;
  for (int kt = 0; kt < NK - 1; ++kt, c ^= 1) {
    const long ko = (long)(kt + 1) << 6;
    LOADA(c, 0)
    LOADB(c, 0)
    STAGE_A(c ^ 1, ko)
    BARRIER;
    LGKM0;
    __builtin_amdgcn_s_setprio(1);
    MFMAQ(0, 0)
    __builtin_amdgcn_s_setprio(0);
    BARRIER;
    LOADB(c, 1)
    STAGE_B(c ^ 1, ko)
    BARRIER;
    LGKM0;
    __builtin_amdgcn_s_setprio(1);
    MFMAQ(0, 1)
    __builtin_amdgcn_s_setprio(0);
    BARRIER;
    LOADA(c, 1)
    BARRIER;
    LGKM0;
    __builtin_amdgcn_s_setprio(1);
    MFMAQ(1, 0)
    __builtin_amdgcn_s_setprio(0);
    BARRIER;
    VM0;
    BARRIER;
    __builtin_amdgcn_s_setprio(1);
    MFMAQ(1, 1)
    __builtin_amdgcn_s_setprio(0);
  }
  LOADA(c, 0)
  LOADB(c, 0)
  LOADB(c, 1)
  MFMAQ(0, 0)
  MFMAQ(0, 1)
  LOADA(c, 1)
  MFMAQ(1, 0)
  MFMAQ(1, 1)

  float scl = 1.0f;
  if (MODE == 1) {
    const int iv = scale_ptr[0];
    const float fv = __int_as_float(iv);
    const float sv = (iv > 0 && iv < (1 << 20)) ? (float)iv : fv;
    scl = 1.0f / sv;
  }
  const int rb = tile_m + wm * 128 + ((lane >> 4) << 2);
  const int cb = tile_n + wn * 64 + (lane & 15);
  if (MODE == 2) {
    float* C = reinterpret_cast<float*>(Cvoid) + (long)bz * sC;
#pragma unroll
    for (int mf = 0; mf < 8; ++mf)
#pragma unroll
      for (int nf = 0; nf < 4; ++nf)
#pragma unroll
        for (int r = 0; r < 4; ++r)
          C[(long)(rb + mf * 16 + r) * N + (cb + nf * 16)] = acc[mf][nf][r];
  } else {
    bf16* C = reinterpret_cast<bf16*>(Cvoid) + (long)bz * sC;
#pragma unroll
    for (int nf = 0; nf < 4; ++nf) {
      const int col = cb + nf * 16;
#pragma unroll
      for (int mf = 0; mf < 8; ++mf)
#pragma unroll
        for (int r = 0; r < 4; ++r)
          C[(long)(rb + mf * 16 + r) * N + col] = (bf16)(acc[mf][nf][r] * scl);
    }
  }
}

// -------- projection GEMM: A staged as RAW F32 via global_load_lds, cvt on read -------
// C[m][n] = sum_k A_f32[m][k] * W_bf16[n][k] + bias[n]; z selects (query,bq) / (key,bk).
// 128x256 tile, BK=32, 512 thr = 8 waves (2Mx4N), acc[4][4]. LDS 64KB (2 blocks/CU):
// per buf 32KB = A f32 [128][32] (16KB) + B bf16 [256][32] (16KB).
// A: gload_lds moves raw f32 bytes (async path intact -- fixes R8's reg-staging stall);
// fragment read = 2x ds_read_b128 f32 + 8 cvt per frag. Swizzle (8 chunks/row f32):
// slot(row,kc) holds global chunk kc^(row&7); read physical = logical^(frow&7)
// (lane-constant). B: byte-identical to R5-measured 0-conflict path.
__global__ __launch_bounds__(512, 4)
void gemm_proj(const float* __restrict__ Aq, const float* __restrict__ Ak,
               const bf16* __restrict__ Wb, const float* __restrict__ bias0,
               const float* __restrict__ bias1, bf16* __restrict__ Cout,
               int N, int K, long sB, long sC) {
  __shared__ bf16 lds[32768];  // 64 KB; buf stride 32KB = 16384 bf16 / 8192 f32
  const int t = threadIdx.x;
  const int lane = t & 63;
  const int wid = t >> 6;
  const int wm = wid >> 2;
  const int wn = wid & 3;

  const int gx = gridDim.x, gy = gridDim.y;
  const int nwg = gx * gy * gridDim.z;
  int id = blockIdx.x + gx * (blockIdx.y + gy * blockIdx.z);
  {
    const int cpx = nwg >> 3;
    id = (id & 7) * cpx + (id >> 3);
  }
  const int bx = id % gx;
  const int by = (id / gx) % gy;
  const int bz = id / (gx * gy);

  const float* Af = bz ? Ak : Aq;
  const bf16* Bb = Wb + (long)bz * sB;
  const int tile_m = by * 128;
  const int tile_n = bx * 256;

  // A staging: [128][32] f32 = 1024 x 16B chunks (8/row); thread t covers chunk t
  // (row=t>>3, kc=t&7) and t+512 (row+64, same swizzle). Source chunk = kc^(row&7).
  const int ar = t >> 3;
  const int akc = t & 7;
  const float* gA0 = Af + (long)(tile_m + ar) * K + ((akc ^ (ar & 7)) << 2);
  const long aK64 = (long)K << 6;    // +64 rows (floats)
  float* const ldsAf = reinterpret_cast<float*>(&lds[0]);
  float* const aDst = ldsAf + wid * 256;   // chunk t dest (+HW lane*16B); +2048 for t+512

  // B staging: [256][32] bf16 = 1024 chunks (4/row); thread t covers chunk t
  // (row=t>>2, kc=t&3) and t+512 (row+128). Source chunk = kc ^ ((row>>1)&3).
  const int br = t >> 2;
  const int bkc = t & 3;
  const bf16* gB0 = Bb + (long)(tile_n + br) * K + ((bkc ^ ((br >> 1) & 3)) << 3);
  const long rK128 = (long)K << 7;   // +128 rows (bf16)
  bf16* const bDst = &lds[8192 * 2] + wid * 512;  // B base = byte 16384 = bf16 idx 8192? (see note)

  // NOTE: lds is bf16[32768] = 64KB. Buf b: A f32 at bytes [b*32768, +16384) ->
  // float idx b*8192; B bf16 at bytes [b*32768+16384, +32768) -> bf16 idx b*16384+8192.
  // bDst above must be &lds[8192] (bf16 idx 8192 = byte 16384). Fix:
  // (kept as named pointer below)

  const int frow = lane & 15;
  const int fj = lane >> 4;  // 0..3
  const int pa0 = (((2 * fj) ^ (frow & 7)) << 2);       // float offset of 1st chunk
  const int pa1 = (((2 * fj + 1) ^ (frow & 7)) << 2);   // float offset of 2nd chunk
  const float* aF = ldsAf + (wm * 64 + frow) * 32;
  const int pko = ((fj ^ ((lane >> 1) & 3)) << 3);      // bf16 offset (R5-verified)
  const bf16* bF = &lds[8192] + (wn * 64 + frow) * 32 + pko;
  bf16* const bDstFix = &lds[8192] + wid * 512;

  bf16x8 a[4], b[4];
  f32x4 acc[4][4] = {};

#define PSTAGE(buf, ko)                                                \
  {                                                                    \
    gload_lds16(gA0 + (ko), aDst + (buf) * 8192);                      \
    gload_lds16(gA0 + (ko) + aK64, aDst + (buf) * 8192 + 2048);        \
    gload_lds16(gB0 + (ko), bDstFix + (buf) * 16384);                  \
    gload_lds16(gB0 + (ko) + rK128, bDstFix + (buf) * 16384 + 4096);   \
  }

  PSTAGE(0, 0)
  __syncthreads();

  const int NK = K >> 5;
  int c = 0;
  for (int kt = 0; kt < NK - 1; ++kt, c ^= 1) {
    PSTAGE(c ^ 1, (kt + 1) * 32)
#pragma unroll
    for (int n_ = 0; n_ < 4; ++n_)
      b[n_] = *reinterpret_cast<const bf16x8*>(bF + c * 16384 + n_ * 512);
#pragma unroll
    for (int m_ = 0; m_ < 4; ++m_) {
      const float* p_ = aF + c * 8192 + m_ * 512;
      float4 fa = *reinterpret_cast<const float4*>(p_ + pa0);
      float4 fb = *reinterpret_cast<const float4*>(p_ + pa1);
      bf16x8 av;
      av[0] = (bf16)fa.x; av[1] = (bf16)fa.y; av[2] = (bf16)fa.z; av[3] = (bf16)fa.w;
      av[4] = (bf16)fb.x; av[5] = (bf16)fb.y; av[6] = (bf16)fb.z; av[7] = (bf16)fb.w;
      a[m_] = av;
    }
#pragma unroll
    for (int m_ = 0; m_ < 4; ++m_)
#pragma unroll
      for (int n_ = 0; n_ < 4; ++n_)
        acc[m_][n_] = __builtin_amdgcn_mfma_f32_16x16x32_bf16(a[m_], b[n_], acc[m_][n_], 0, 0, 0);
    __syncthreads();
  }
  // peeled last tile
#pragma unroll
  for (int n_ = 0; n_ < 4; ++n_)
    b[n_] = *reinterpret_cast<const bf16x8*>(bF + c * 16384 + n_ * 512);
#pragma unroll
  for (int m_ = 0; m_ < 4; ++m_) {
    const float* p_ = aF + c * 8192 + m_ * 512;
    float4 fa = *reinterpret_cast<const float4*>(p_ + pa0);
    float4 fb = *reinterpret_cast<const float4*>(p_ + pa1);
    bf16x8 av;
    av[0] = (bf16)fa.x; av[1] = (bf16)fa.y; av[2] = (bf16)fa.z; av[3] = (bf16)fa.w;
    av[4] = (bf16)fb.x; av[5] = (bf16)fb.y; av[6] = (bf16)fb.z; av[7] = (bf16)fb.w;
    a[m_] = av;
  }
#pragma unroll
  for (int m_ = 0; m_ < 4; ++m_)
#pragma unroll
    for (int n_ = 0; n_ < 4; ++n_)
      acc[m_][n_] = __builtin_amdgcn_mfma_f32_16x16x32_bf16(a[m_], b[n_], acc[m_][n_], 0, 0, 0);

  const float* bias = bz ? bias1 : bias0;
  const int rb = tile_m + wm * 64 + ((lane >> 4) << 2);
  const int cb = tile_n + wn * 64 + (lane & 15);
  bf16* C = Cout + (long)bz * sC;
#pragma unroll
  for (int nf = 0; nf < 4; ++nf) {
    const int col = cb + nf * 16;
    const float bv = bias[col];
#pragma unroll
    for (int mf = 0; mf < 4; ++mf)
#pragma unroll
      for (int r = 0; r < 4; ++r)
        C[(long)(rb + mf * 16 + r) * N + col] = (bf16)(acc[mf][nf][r] + bv);
  }
#undef PSTAGE
}

extern "C" void kernel_launch(void* const* d_in, const int* in_sizes, int n_in,
                              void* d_out, int out_size, void* d_ws, size_t ws_size,
                              hipStream_t stream) {
  (void)in_sizes; (void)n_in; (void)out_size; (void)ws_size;
  const float* query = (const float*)d_in[0];
  const float* key   = (const float*)d_in[1];
  const float* value = (const float*)d_in[2];
  const float* Wq    = (const float*)d_in[3];
  const float* bq    = (const float*)d_in[4];
  const float* Wk    = (const float*)d_in[5];
  const float* bk    = (const float*)d_in[6];
  const int*   scale = (const int*)d_in[7];

  const int L = 2048, D = 1024;
  // ws layout (bytes):
  //   [0,   64M): S/P (8*2048*2048 bf16 = 64M exactly)
  //   [64M, 96M): Qp   [96M,128M): Kp   [128M,160M): VT
  //   [160M,162M): Wq_b  [162M,164M): Wk_b (contiguous, stride 1048576 elems)
  char* ws = (char*)d_ws;
  bf16* S      = (bf16*)ws;
  bf16* Qp     = (bf16*)(ws + (size_t)67108864);
  bf16* Kp     = (bf16*)(ws + (size_t)100663296);
  bf16* VT     = (bf16*)(ws + (size_t)134217728);
  bf16* Wqb    = (bf16*)(ws + (size_t)167772160);
  bf16* Wkb    = (bf16*)(ws + (size_t)169869312);

  cast_f32_bf16<<<1024, 256, 0, stream>>>(Wq, Wqb, 262144);
  cast_f32_bf16<<<1024, 256, 0, stream>>>(Wk, Wkb, 262144);
  transpose_cast<<<dim3(16, 32, 8), 256, 0, stream>>>(value, VT, 2048, 1024);

  // projections with fused cast (z=0 -> Q, z=1 -> K): M=16384, N=1024, K=1024
  gemm_proj<<<dim3(4, 128, 2), 512, 0, stream>>>(query, key, Wqb, bq, bk, Qp,
                                                 1024, 1024, 1048576L, 16777216L);
  // scores: S[b] = (Qp[b] @ Kp[b]^T) / scale   (M=N=2048, K=1024, batched over 8)
  gemm_bt<1><<<dim3(8, 8, 8), 512, 0, stream>>>(Qp, Kp, S, scale,
                                                2048, 1024,
                                                (long)L * D, (long)L * D, (long)L * L);
  softmax_rows<<<16384, 256, 0, stream>>>(S);
  // out: O[b] = P[b] @ VT[b]^T  (M=2048, N=1024, K=2048, f32 out)
  gemm_bt<2><<<dim3(4, 8, 8), 512, 0, stream>>>(S, VT, d_out, nullptr,
                                                1024, 2048,
                                                (long)L * L, (long)D * L, (long)L * D);
}

// Round 10
// 282.285 us; speedup vs baseline: 1.0821x; 1.0821x over previous
//
#include <hip/hip_runtime.h>

typedef __bf16 bf16;
typedef __attribute__((ext_vector_type(4))) __bf16 bf16x4;
typedef __attribute__((ext_vector_type(8))) __bf16 bf16x8;
typedef __attribute__((ext_vector_type(4))) float f32x4;

__device__ __forceinline__ void gload_lds16(const void* g, void* l) {
  __builtin_amdgcn_global_load_lds(
      (const __attribute__((address_space(1))) unsigned int*)(unsigned long long)g,
      (__attribute__((address_space(3))) unsigned int*)(unsigned long long)l,
      16, 0, 0);
}

// ---------------- cast fp32 -> bf16, two tensors per launch (z selects) ----------------
__global__ void cast2_f32_bf16(const float* __restrict__ in0, bf16* __restrict__ out0,
                               const float* __restrict__ in1, bf16* __restrict__ out1,
                               int n4) {
  int i = blockIdx.x * blockDim.x + threadIdx.x;
  if (i >= n4) return;
  const float* in = blockIdx.z ? in1 : in0;
  bf16* out = blockIdx.z ? out1 : out0;
  float4 v = reinterpret_cast<const float4*>(in)[i];
  bf16x4 o;
  o[0] = (bf16)v.x; o[1] = (bf16)v.y; o[2] = (bf16)v.z; o[3] = (bf16)v.w;
  reinterpret_cast<bf16x4*>(out)[i] = o;
}

// ------- transpose+cast: V (rows x cols, f32) -> VT (cols x rows, bf16), batched -------
__global__ void transpose_cast(const float* __restrict__ V, bf16* __restrict__ VT,
                               int rows, int cols) {
  __shared__ bf16 tile[64][65];
  const int b = blockIdx.z;
  const float* Vb = V + (long)b * rows * cols;
  bf16* VTb = VT + (long)b * rows * cols;
  const int d0 = blockIdx.x * 64;
  const int k0 = blockIdx.y * 64;
  const int t = threadIdx.x;
  const int r = t >> 4;
  const int c4 = (t & 15) * 4;
#pragma unroll
  for (int p = 0; p < 4; ++p) {
    float4 v = *reinterpret_cast<const float4*>(&Vb[(long)(k0 + p * 16 + r) * cols + d0 + c4]);
    tile[p * 16 + r][c4 + 0] = (bf16)v.x;
    tile[p * 16 + r][c4 + 1] = (bf16)v.y;
    tile[p * 16 + r][c4 + 2] = (bf16)v.z;
    tile[p * 16 + r][c4 + 3] = (bf16)v.w;
  }
  __syncthreads();
#pragma unroll
  for (int p = 0; p < 4; ++p) {
    const int dd = p * 16 + r;
    bf16x4 o;
    o[0] = tile[c4 + 0][dd];
    o[1] = tile[c4 + 1][dd];
    o[2] = tile[c4 + 2][dd];
    o[3] = tile[c4 + 3][dd];
    *reinterpret_cast<bf16x4*>(&VTb[(long)(d0 + dd) * rows + k0 + c4]) = o;
  }
}

// ---------------- in-place row softmax, row length 2048, bf16 ----------------
__global__ void softmax_rows(bf16* __restrict__ S) {
  const long row = blockIdx.x;
  bf16* p = S + row * 2048;
  const int t = threadIdx.x;
  const int wid = t >> 6;
  const int lane = t & 63;
  bf16x8 v = *reinterpret_cast<bf16x8*>(p + t * 8);
  float f[8];
  float m = -3.0e38f;
#pragma unroll
  for (int j = 0; j < 8; ++j) { f[j] = (float)v[j]; m = fmaxf(m, f[j]); }
#pragma unroll
  for (int off = 32; off >= 1; off >>= 1) m = fmaxf(m, __shfl_xor(m, off));
  __shared__ float redm[4], reds[4];
  if (lane == 0) redm[wid] = m;
  __syncthreads();
  m = fmaxf(fmaxf(redm[0], redm[1]), fmaxf(redm[2], redm[3]));
  float s = 0.f;
#pragma unroll
  for (int j = 0; j < 8; ++j) { f[j] = __expf(f[j] - m); s += f[j]; }
#pragma unroll
  for (int off = 32; off >= 1; off >>= 1) s += __shfl_xor(s, off);
  if (lane == 0) reds[wid] = s;
  __syncthreads();
  s = reds[0] + reds[1] + reds[2] + reds[3];
  const float inv = 1.0f / s;
  bf16x8 o;
#pragma unroll
  for (int j = 0; j < 8; ++j) o[j] = (bf16)(f[j] * inv);
  *reinterpret_cast<bf16x8*>(p + t * 8) = o;
}

// ---------------- B^T GEMM, 256x256 tile, BK=64, 8-phase (R2 core, best measured) ------
// 512 threads = 8 waves (2 M x 4 N), each wave owns a 128x64 output sub-tile.
// LDS [buf2][op2][half2][128][64] bf16 = 128 KiB, XOR chunk swizzle kc^(row&7)
// (R2-measured: 0 bank conflicts, 97.1-97.6 us per 68.7-GFLOP launch, 289.0 us total).
// MODE 0: bf16 out + bias; MODE 1: bf16 out * (1/scale); MODE 2: f32 out.

#define BARRIER __builtin_amdgcn_s_barrier()
#define LGKM0                                              \
  do {                                                     \
    asm volatile("s_waitcnt lgkmcnt(0)" ::: "memory");     \
    __builtin_amdgcn_sched_barrier(0);                     \
  } while (0)
#define VM0                                                \
  do {                                                     \
    asm volatile("s_waitcnt vmcnt(0)" ::: "memory");       \
    __builtin_amdgcn_sched_barrier(0);                     \
  } while (0)

#define STAGE_A(buf, ko)                                        \
  {                                                             \
    bf16* l_ = ldsd + (buf) * 32768;                            \
    const bf16* g_ = gA + (ko);                                 \
    gload_lds16(g_, l_);                                        \
    gload_lds16(g_ + rK64, l_ + 4096);                          \
    gload_lds16(g_ + rK128, l_ + 8192);                         \
    gload_lds16(g_ + rK128 + rK64, l_ + 12288);                 \
  }
#define STAGE_B(buf, ko)                                        \
  {                                                             \
    bf16* l_ = ldsd + (buf) * 32768 + 16384;                    \
    const bf16* g_ = gB + (ko);                                 \
    gload_lds16(g_, l_);                                        \
    gload_lds16(g_ + rK64, l_ + 4096);                          \
    gload_lds16(g_ + rK128, l_ + 8192);                         \
    gload_lds16(g_ + rK128 + rK64, l_ + 12288);                 \
  }

#define LOADA(buf, mq)                                                        \
  {                                                                           \
    const bf16* p_ = aBase + (buf) * 32768 + (mq) * 4096;                     \
    _Pragma("unroll") for (int m_ = 0; m_ < 4; ++m_) {                        \
      a[m_][0] = *reinterpret_cast<const bf16x8*>(p_ + m_ * 1024 + pk0);      \
      a[m_][1] = *reinterpret_cast<const bf16x8*>(p_ + m_ * 1024 + pk1);      \
    }                                                                         \
  }
#define LOADB(buf, nq)                                                        \
  {                                                                           \
    const bf16* p_ = bBase + (buf) * 32768 + (nq) * 2048;                     \
    _Pragma("unroll") for (int n_ = 0; n_ < 2; ++n_) {                        \
      b[(nq) * 2 + n_][0] = *reinterpret_cast<const bf16x8*>(p_ + n_ * 1024 + pk0); \
      b[(nq) * 2 + n_][1] = *reinterpret_cast<const bf16x8*>(p_ + n_ * 1024 + pk1); \
    }                                                                         \
  }

#define MFMAQ(mq, nq)                                                         \
  _Pragma("unroll") for (int m_ = 0; m_ < 4; ++m_)                            \
  _Pragma("unroll") for (int n_ = 0; n_ < 2; ++n_)                            \
  _Pragma("unroll") for (int ks_ = 0; ks_ < 2; ++ks_)                         \
      acc[(mq) * 4 + m_][(nq) * 2 + n_] =                                     \
          __builtin_amdgcn_mfma_f32_16x16x32_bf16(                            \
              a[m_][ks_], b[(nq) * 2 + n_][ks_],                              \
              acc[(mq) * 4 + m_][(nq) * 2 + n_], 0, 0, 0);

template <int MODE>
__global__ __launch_bounds__(512, 2)
void gemm_bt(const bf16* __restrict__ A, const bf16* __restrict__ Bm,
             const float* __restrict__ bias, void* __restrict__ Cvoid,
             const int* __restrict__ scale_ptr,
             int M, int N, int K, long sA, long sB, long sC) {
  __shared__ bf16 lds[2][2][2][128][64];  // [buf][opA/B][half][row][64k] = 128 KiB
  const int t = threadIdx.x;
  const int lane = t & 63;
  const int wid = t >> 6;   // 0..7
  const int wm = wid >> 2;  // 0..1
  const int wn = wid & 3;   // 0..3
  (void)M;

  // XCD-aware bijective swizzle (all grids here have nwg % 8 == 0)
  const int gx = gridDim.x, gy = gridDim.y;
  const int nwg = gx * gy * gridDim.z;
  int id = blockIdx.x + gx * (blockIdx.y + gy * blockIdx.z);
  {
    const int cpx = nwg >> 3;
    id = (id & 7) * cpx + (id >> 3);
  }
  const int bx = id % gx;
  const int by = (id / gx) % gy;
  const int bz = id / (gx * gy);

  const bf16* Ab = A + (long)bz * sA;
  const bf16* Bb = Bm + (long)bz * sB;
  const int tile_m = by * 256;
  const int tile_n = bx * 256;

  // staging: half-tile = [128][64] = 1024 x 16B chunks; thread t covers chunk t
  // (row=t>>3, kc=t&7) and chunk t+512 (row+64). Source pre-swizzled: global
  // chunk = kc ^ (row&7). Dest linear: elem = chunk*8 (wave-uniform + lane*16B).
  const int srow = t >> 3;
  const int skc = t & 7;
  const int soff = ((skc ^ (srow & 7)) << 3);
  const bf16* gA = Ab + (long)(tile_m + srow) * K + soff;
  const bf16* gB = Bb + (long)(tile_n + srow) * K + soff;
  const long rK64 = (long)K << 6;    // +64 rows
  const long rK128 = (long)K << 7;   // +128 rows (half stride)
  bf16* const ldsd = &lds[0][0][0][0][0] + wid * 512;

  // fragment reads: lane reads row frow=lane&15 of its half, logical k-chunk
  // ks*4+(lane>>4); physical chunk = logical ^ (row&7) = logical ^ (lane&7).
  const int frow = lane & 15;
  const int pk0 = (((lane >> 4) ^ (lane & 7))) << 3;
  const int pk1 = (((4 | (lane >> 4)) ^ (lane & 7))) << 3;
  const bf16* aBase = &lds[0][0][wm][frow][0];
  const bf16* bBase = &lds[0][1][wn >> 1][(wn & 1) * 64 + frow][0];

  bf16x8 a[4][2], b[4][2];
  f32x4 acc[8][4] = {};

  // prologue: stage tile 0 fully, drain once, sync
  STAGE_A(0, 0)
  STAGE_B(0, 0)
  VM0;
  BARRIER;

  const int NK = K >> 6;
  int c = 0;
  for (int kt = 0; kt < NK - 1; ++kt, c ^= 1) {
    const long ko = (long)(kt + 1) << 6;
    // P0: quadrant (0,0); prefetch A of kt+1
    LOADA(c, 0)
    LOADB(c, 0)
    STAGE_A(c ^ 1, ko)
    BARRIER;
    LGKM0;
    __builtin_amdgcn_s_setprio(1);
    MFMAQ(0, 0)
    __builtin_amdgcn_s_setprio(0);
    BARRIER;
    // P1: quadrant (0,1); prefetch B of kt+1
    LOADB(c, 1)
    STAGE_B(c ^ 1, ko)
    BARRIER;
    LGKM0;
    __builtin_amdgcn_s_setprio(1);
    MFMAQ(0, 1)
    __builtin_amdgcn_s_setprio(0);
    BARRIER;
    // P2: quadrant (1,0)
    LOADA(c, 1)
    BARRIER;
    LGKM0;
    __builtin_amdgcn_s_setprio(1);
    MFMAQ(1, 0)
    __builtin_amdgcn_s_setprio(0);
    BARRIER;
    // P3: boundary — drain kt+1's loads (issued 2-3 phases ago), sync, last quadrant
    VM0;
    BARRIER;
    __builtin_amdgcn_s_setprio(1);
    MFMAQ(1, 1)
    __builtin_amdgcn_s_setprio(0);
  }
  // peeled last tile: pure compute from buf c (no staging, compiler-managed waits)
  LOADA(c, 0)
  LOADB(c, 0)
  LOADB(c, 1)
  MFMAQ(0, 0)
  MFMAQ(0, 1)
  LOADA(c, 1)
  MFMAQ(1, 0)
  MFMAQ(1, 1)

  float scl = 1.0f;
  if (MODE == 1) {
    const int iv = scale_ptr[0];
    const float fv = __int_as_float(iv);
    const float sv = (iv > 0 && iv < (1 << 20)) ? (float)iv : fv;
    scl = 1.0f / sv;
  }
  // C/D layout (verified m89/m91): col=lane&15, row=(lane>>4)*4+reg
  const int rb = tile_m + wm * 128 + ((lane >> 4) << 2);
  const int cb = tile_n + wn * 64 + (lane & 15);
  if (MODE == 2) {
    float* C = reinterpret_cast<float*>(Cvoid) + (long)bz * sC;
#pragma unroll
    for (int mf = 0; mf < 8; ++mf)
#pragma unroll
      for (int nf = 0; nf < 4; ++nf)
#pragma unroll
        for (int r = 0; r < 4; ++r)
          C[(long)(rb + mf * 16 + r) * N + (cb + nf * 16)] = acc[mf][nf][r];
  } else {
    bf16* C = reinterpret_cast<bf16*>(Cvoid) + (long)bz * sC;
#pragma unroll
    for (int nf = 0; nf < 4; ++nf) {
      const int col = cb + nf * 16;
      const float bv = (MODE == 0) ? bias[col] : 0.0f;
#pragma unroll
      for (int mf = 0; mf < 8; ++mf)
#pragma unroll
        for (int r = 0; r < 4; ++r)
          C[(long)(rb + mf * 16 + r) * N + col] = (bf16)(acc[mf][nf][r] * scl + bv);
    }
  }
}

extern "C" void kernel_launch(void* const* d_in, const int* in_sizes, int n_in,
                              void* d_out, int out_size, void* d_ws, size_t ws_size,
                              hipStream_t stream) {
  (void)in_sizes; (void)n_in; (void)out_size; (void)ws_size;
  const float* query = (const float*)d_in[0];
  const float* key   = (const float*)d_in[1];
  const float* value = (const float*)d_in[2];
  const float* Wq    = (const float*)d_in[3];
  const float* bq    = (const float*)d_in[4];
  const float* Wk    = (const float*)d_in[5];
  const float* bk    = (const float*)d_in[6];
  const int*   scale = (const int*)d_in[7];

  const int L = 2048, D = 1024;
  // ws layout (bytes):
  //   [0,   64M): q_cast(32M) + k_cast(32M), later reused as S/P (8*2048*2048 bf16 = 64M exactly)
  //   [64M, 96M): Qp   [96M,128M): Kp   [128M,160M): VT   [160M,162M): Wq_b  [162M,164M): Wk_b
  char* ws = (char*)d_ws;
  bf16* q_cast = (bf16*)ws;
  bf16* k_cast = q_cast + (long)16384 * 1024;
  bf16* S      = q_cast;
  bf16* Qp     = (bf16*)(ws + (size_t)67108864);
  bf16* Kp     = (bf16*)(ws + (size_t)100663296);
  bf16* VT     = (bf16*)(ws + (size_t)134217728);
  bf16* Wqb    = (bf16*)(ws + (size_t)167772160);
  bf16* Wkb    = (bf16*)(ws + (size_t)169869312);

  // merged casts: q+k in one launch, Wq+Wk in another (z selects tensor)
  cast2_f32_bf16<<<dim3(16384, 1, 2), 256, 0, stream>>>(query, q_cast, key, k_cast, 4194304);
  cast2_f32_bf16<<<dim3(1024, 1, 2), 256, 0, stream>>>(Wq, Wqb, Wk, Wkb, 262144);
  transpose_cast<<<dim3(16, 32, 8), 256, 0, stream>>>(value, VT, 2048, 1024);

  // projections: Qp = q_cast @ Wq^T + bq   (M=16384, N=1024, K=1024)
  gemm_bt<0><<<dim3(4, 64, 1), 512, 0, stream>>>(q_cast, Wqb, bq, Qp, nullptr,
                                                 16384, 1024, 1024, 0, 0, 0);
  gemm_bt<0><<<dim3(4, 64, 1), 512, 0, stream>>>(k_cast, Wkb, bk, Kp, nullptr,
                                                 16384, 1024, 1024, 0, 0, 0);
  // scores: S[b] = (Qp[b] @ Kp[b]^T) / scale   (M=N=2048, K=1024, batched over 8)
  gemm_bt<1><<<dim3(8, 8, 8), 512, 0, stream>>>(Qp, Kp, nullptr, S, scale,
                                                2048, 2048, 1024,
                                                (long)L * D, (long)L * D, (long)L * L);
  softmax_rows<<<16384, 256, 0, stream>>>(S);
  // out: O[b] = P[b] @ VT[b]^T  (M=2048, N=1024, K=2048, f32 out)
  gemm_bt<2><<<dim3(4, 8, 8), 512, 0, stream>>>(S, VT, nullptr, d_out, nullptr,
                                                2048, 1024, 2048,
                                                (long)L * L, (long)D * L, (long)L * D);
}

// Round 11
// 278.296 us; speedup vs baseline: 1.0976x; 1.0143x over previous
//
#include <hip/hip_runtime.h>

typedef __bf16 bf16;
typedef __attribute__((ext_vector_type(4))) __bf16 bf16x4;
typedef __attribute__((ext_vector_type(8))) __bf16 bf16x8;
typedef __attribute__((ext_vector_type(4))) float f32x4;

__device__ __forceinline__ void gload_lds16(const void* g, void* l) {
  __builtin_amdgcn_global_load_lds(
      (const __attribute__((address_space(1))) unsigned int*)(unsigned long long)g,
      (__attribute__((address_space(3))) unsigned int*)(unsigned long long)l,
      16, 0, 0);
}

// ---------------- cast fp32 -> bf16, two tensors per launch (z selects) ----------------
__global__ void cast2_f32_bf16(const float* __restrict__ in0, bf16* __restrict__ out0,
                               const float* __restrict__ in1, bf16* __restrict__ out1,
                               int n4) {
  int i = blockIdx.x * blockDim.x + threadIdx.x;
  if (i >= n4) return;
  const float* in = blockIdx.z ? in1 : in0;
  bf16* out = blockIdx.z ? out1 : out0;
  float4 v = reinterpret_cast<const float4*>(in)[i];
  bf16x4 o;
  o[0] = (bf16)v.x; o[1] = (bf16)v.y; o[2] = (bf16)v.z; o[3] = (bf16)v.w;
  reinterpret_cast<bf16x4*>(out)[i] = o;
}

// ------- transpose+cast: V (rows x cols, f32) -> VT (cols x rows, bf16), batched -------
__global__ void transpose_cast(const float* __restrict__ V, bf16* __restrict__ VT,
                               int rows, int cols) {
  __shared__ bf16 tile[64][65];
  const int b = blockIdx.z;
  const float* Vb = V + (long)b * rows * cols;
  bf16* VTb = VT + (long)b * rows * cols;
  const int d0 = blockIdx.x * 64;
  const int k0 = blockIdx.y * 64;
  const int t = threadIdx.x;
  const int r = t >> 4;
  const int c4 = (t & 15) * 4;
#pragma unroll
  for (int p = 0; p < 4; ++p) {
    float4 v = *reinterpret_cast<const float4*>(&Vb[(long)(k0 + p * 16 + r) * cols + d0 + c4]);
    tile[p * 16 + r][c4 + 0] = (bf16)v.x;
    tile[p * 16 + r][c4 + 1] = (bf16)v.y;
    tile[p * 16 + r][c4 + 2] = (bf16)v.z;
    tile[p * 16 + r][c4 + 3] = (bf16)v.w;
  }
  __syncthreads();
#pragma unroll
  for (int p = 0; p < 4; ++p) {
    const int dd = p * 16 + r;
    bf16x4 o;
    o[0] = tile[c4 + 0][dd];
    o[1] = tile[c4 + 1][dd];
    o[2] = tile[c4 + 2][dd];
    o[3] = tile[c4 + 3][dd];
    *reinterpret_cast<bf16x4*>(&VTb[(long)(d0 + dd) * rows + k0 + c4]) = o;
  }
}

// ---------------- in-place row softmax, row length 2048, bf16 ----------------
__global__ void softmax_rows(bf16* __restrict__ S) {
  const long row = blockIdx.x;
  bf16* p = S + row * 2048;
  const int t = threadIdx.x;
  const int wid = t >> 6;
  const int lane = t & 63;
  bf16x8 v = *reinterpret_cast<bf16x8*>(p + t * 8);
  float f[8];
  float m = -3.0e38f;
#pragma unroll
  for (int j = 0; j < 8; ++j) { f[j] = (float)v[j]; m = fmaxf(m, f[j]); }
#pragma unroll
  for (int off = 32; off >= 1; off >>= 1) m = fmaxf(m, __shfl_xor(m, off));
  __shared__ float redm[4], reds[4];
  if (lane == 0) redm[wid] = m;
  __syncthreads();
  m = fmaxf(fmaxf(redm[0], redm[1]), fmaxf(redm[2], redm[3]));
  float s = 0.f;
#pragma unroll
  for (int j = 0; j < 8; ++j) { f[j] = __expf(f[j] - m); s += f[j]; }
#pragma unroll
  for (int off = 32; off >= 1; off >>= 1) s += __shfl_xor(s, off);
  if (lane == 0) reds[wid] = s;
  __syncthreads();
  s = reds[0] + reds[1] + reds[2] + reds[3];
  const float inv = 1.0f / s;
  bf16x8 o;
#pragma unroll
  for (int j = 0; j < 8; ++j) o[j] = (bf16)(f[j] * inv);
  *reinterpret_cast<bf16x8*>(p + t * 8) = o;
}

// ---------------- B^T GEMM, 256x256 tile, BK=64, 8-phase (R2 core, best measured) ------
// 512 threads = 8 waves (2 M x 4 N), each wave owns a 128x64 output sub-tile.
// LDS [buf2][op2][half2][128][64] bf16 = 128 KiB, XOR chunk swizzle kc^(row&7)
// (measured: 0 bank conflicts, 97-99 us per 68.7-GFLOP launch; 282.3 us total @R10).
// MODE 0: bf16 out + bias (bz selects bias0/bias1); MODE 1: bf16 * (1/scale); MODE 2: f32.

#define BARRIER __builtin_amdgcn_s_barrier()
#define LGKM0                                              \
  do {                                                     \
    asm volatile("s_waitcnt lgkmcnt(0)" ::: "memory");     \
    __builtin_amdgcn_sched_barrier(0);                     \
  } while (0)
#define VM0                                                \
  do {                                                     \
    asm volatile("s_waitcnt vmcnt(0)" ::: "memory");       \
    __builtin_amdgcn_sched_barrier(0);                     \
  } while (0)

#define STAGE_A(buf, ko)                                        \
  {                                                             \
    bf16* l_ = ldsd + (buf) * 32768;                            \
    const bf16* g_ = gA + (ko);                                 \
    gload_lds16(g_, l_);                                        \
    gload_lds16(g_ + rK64, l_ + 4096);                          \
    gload_lds16(g_ + rK128, l_ + 8192);                         \
    gload_lds16(g_ + rK128 + rK64, l_ + 12288);                 \
  }
#define STAGE_B(buf, ko)                                        \
  {                                                             \
    bf16* l_ = ldsd + (buf) * 32768 + 16384;                    \
    const bf16* g_ = gB + (ko);                                 \
    gload_lds16(g_, l_);                                        \
    gload_lds16(g_ + rK64, l_ + 4096);                          \
    gload_lds16(g_ + rK128, l_ + 8192);                         \
    gload_lds16(g_ + rK128 + rK64, l_ + 12288);                 \
  }

#define LOADA(buf, mq)                                                        \
  {                                                                           \
    const bf16* p_ = aBase + (buf) * 32768 + (mq) * 4096;                     \
    _Pragma("unroll") for (int m_ = 0; m_ < 4; ++m_) {                        \
      a[m_][0] = *reinterpret_cast<const bf16x8*>(p_ + m_ * 1024 + pk0);      \
      a[m_][1] = *reinterpret_cast<const bf16x8*>(p_ + m_ * 1024 + pk1);      \
    }                                                                         \
  }
#define LOADB(buf, nq)                                                        \
  {                                                                           \
    const bf16* p_ = bBase + (buf) * 32768 + (nq) * 2048;                     \
    _Pragma("unroll") for (int n_ = 0; n_ < 2; ++n_) {                        \
      b[(nq) * 2 + n_][0] = *reinterpret_cast<const bf16x8*>(p_ + n_ * 1024 + pk0); \
      b[(nq) * 2 + n_][1] = *reinterpret_cast<const bf16x8*>(p_ + n_ * 1024 + pk1); \
    }                                                                         \
  }

#define MFMAQ(mq, nq)                                                         \
  _Pragma("unroll") for (int m_ = 0; m_ < 4; ++m_)                            \
  _Pragma("unroll") for (int n_ = 0; n_ < 2; ++n_)                            \
  _Pragma("unroll") for (int ks_ = 0; ks_ < 2; ++ks_)                         \
      acc[(mq) * 4 + m_][(nq) * 2 + n_] =                                     \
          __builtin_amdgcn_mfma_f32_16x16x32_bf16(                            \
              a[m_][ks_], b[(nq) * 2 + n_][ks_],                              \
              acc[(mq) * 4 + m_][(nq) * 2 + n_], 0, 0, 0);

template <int MODE>
__global__ __launch_bounds__(512, 2)
void gemm_bt(const bf16* __restrict__ A, const bf16* __restrict__ Bm,
             const float* __restrict__ bias0, const float* __restrict__ bias1,
             void* __restrict__ Cvoid, const int* __restrict__ scale_ptr,
             int N, int K, long sA, long sB, long sC) {
  __shared__ bf16 lds[2][2][2][128][64];  // [buf][opA/B][half][row][64k] = 128 KiB
  const int t = threadIdx.x;
  const int lane = t & 63;
  const int wid = t >> 6;   // 0..7
  const int wm = wid >> 2;  // 0..1
  const int wn = wid & 3;   // 0..3

  // XCD-aware bijective swizzle (all grids here have nwg % 8 == 0)
  const int gx = gridDim.x, gy = gridDim.y;
  const int nwg = gx * gy * gridDim.z;
  int id = blockIdx.x + gx * (blockIdx.y + gy * blockIdx.z);
  {
    const int cpx = nwg >> 3;
    id = (id & 7) * cpx + (id >> 3);
  }
  const int bx = id % gx;
  const int by = (id / gx) % gy;
  const int bz = id / (gx * gy);

  const bf16* Ab = A + (long)bz * sA;
  const bf16* Bb = Bm + (long)bz * sB;
  const int tile_m = by * 256;
  const int tile_n = bx * 256;

  // staging: half-tile = [128][64] = 1024 x 16B chunks; thread t covers chunk t
  // (row=t>>3, kc=t&7) and chunk t+512 (row+64). Source pre-swizzled: global
  // chunk = kc ^ (row&7). Dest linear: elem = chunk*8 (wave-uniform + lane*16B).
  const int srow = t >> 3;
  const int skc = t & 7;
  const int soff = ((skc ^ (srow & 7)) << 3);
  const bf16* gA = Ab + (long)(tile_m + srow) * K + soff;
  const bf16* gB = Bb + (long)(tile_n + srow) * K + soff;
  const long rK64 = (long)K << 6;    // +64 rows
  const long rK128 = (long)K << 7;   // +128 rows (half stride)
  bf16* const ldsd = &lds[0][0][0][0][0] + wid * 512;

  // fragment reads: lane reads row frow=lane&15 of its half, logical k-chunk
  // ks*4+(lane>>4); physical chunk = logical ^ (row&7) = logical ^ (lane&7).
  const int frow = lane & 15;
  const int pk0 = (((lane >> 4) ^ (lane & 7))) << 3;
  const int pk1 = (((4 | (lane >> 4)) ^ (lane & 7))) << 3;
  const bf16* aBase = &lds[0][0][wm][frow][0];
  const bf16* bBase = &lds[0][1][wn >> 1][(wn & 1) * 64 + frow][0];

  bf16x8 a[4][2], b[4][2];
  f32x4 acc[8][4] = {};

  // prologue: stage tile 0 fully, drain once, sync
  STAGE_A(0, 0)
  STAGE_B(0, 0)
  VM0;
  BARRIER;

  const int NK = K >> 6;
  int c = 0;
  for (int kt = 0; kt < NK - 1; ++kt, c ^= 1) {
    const long ko = (long)(kt + 1) << 6;
    // P0: quadrant (0,0); prefetch A of kt+1
    LOADA(c, 0)
    LOADB(c, 0)
    STAGE_A(c ^ 1, ko)
    BARRIER;
    LGKM0;
    __builtin_amdgcn_s_setprio(1);
    MFMAQ(0, 0)
    __builtin_amdgcn_s_setprio(0);
    BARRIER;
    // P1: quadrant (0,1); prefetch B of kt+1
    LOADB(c, 1)
    STAGE_B(c ^ 1, ko)
    BARRIER;
    LGKM0;
    __builtin_amdgcn_s_setprio(1);
    MFMAQ(0, 1)
    __builtin_amdgcn_s_setprio(0);
    BARRIER;
    // P2: quadrant (1,0)
    LOADA(c, 1)
    BARRIER;
    LGKM0;
    __builtin_amdgcn_s_setprio(1);
    MFMAQ(1, 0)
    __builtin_amdgcn_s_setprio(0);
    BARRIER;
    // P3: boundary — drain kt+1's loads (issued 2-3 phases ago), sync, last quadrant
    VM0;
    BARRIER;
    __builtin_amdgcn_s_setprio(1);
    MFMAQ(1, 1)
    __builtin_amdgcn_s_setprio(0);
  }
  // peeled last tile: pure compute from buf c (no staging, compiler-managed waits)
  LOADA(c, 0)
  LOADB(c, 0)
  LOADB(c, 1)
  MFMAQ(0, 0)
  MFMAQ(0, 1)
  LOADA(c, 1)
  MFMAQ(1, 0)
  MFMAQ(1, 1)

  float scl = 1.0f;
  if (MODE == 1) {
    const int iv = scale_ptr[0];
    const float fv = __int_as_float(iv);
    const float sv = (iv > 0 && iv < (1 << 20)) ? (float)iv : fv;
    scl = 1.0f / sv;
  }
  // C/D layout (verified m89/m91): col=lane&15, row=(lane>>4)*4+reg
  const int rb = tile_m + wm * 128 + ((lane >> 4) << 2);
  const int cb = tile_n + wn * 64 + (lane & 15);
  if (MODE == 2) {
    float* C = reinterpret_cast<float*>(Cvoid) + (long)bz * sC;
#pragma unroll
    for (int mf = 0; mf < 8; ++mf)
#pragma unroll
      for (int nf = 0; nf < 4; ++nf)
#pragma unroll
        for (int r = 0; r < 4; ++r)
          C[(long)(rb + mf * 16 + r) * N + (cb + nf * 16)] = acc[mf][nf][r];
  } else {
    bf16* C = reinterpret_cast<bf16*>(Cvoid) + (long)bz * sC;
    const float* bias = (MODE == 0) ? (bz ? bias1 : bias0) : nullptr;
#pragma unroll
    for (int nf = 0; nf < 4; ++nf) {
      const int col = cb + nf * 16;
      const float bv = (MODE == 0) ? bias[col] : 0.0f;
#pragma unroll
      for (int mf = 0; mf < 8; ++mf)
#pragma unroll
        for (int r = 0; r < 4; ++r)
          C[(long)(rb + mf * 16 + r) * N + col] = (bf16)(acc[mf][nf][r] * scl + bv);
    }
  }
}

extern "C" void kernel_launch(void* const* d_in, const int* in_sizes, int n_in,
                              void* d_out, int out_size, void* d_ws, size_t ws_size,
                              hipStream_t stream) {
  (void)in_sizes; (void)n_in; (void)out_size; (void)ws_size;
  const float* query = (const float*)d_in[0];
  const float* key   = (const float*)d_in[1];
  const float* value = (const float*)d_in[2];
  const float* Wq    = (const float*)d_in[3];
  const float* bq    = (const float*)d_in[4];
  const float* Wk    = (const float*)d_in[5];
  const float* bk    = (const float*)d_in[6];
  const int*   scale = (const int*)d_in[7];

  const int L = 2048, D = 1024;
  // ws layout (bytes):
  //   [0,   64M): q_cast(32M) + k_cast(32M) [contiguous, stride 16M elems],
  //               later reused as S/P (8*2048*2048 bf16 = 64M exactly)
  //   [64M, 96M): Qp   [96M,128M): Kp [contiguous, stride 16M elems]
  //   [128M,160M): VT   [160M,162M): Wq_b  [162M,164M): Wk_b [contiguous, stride 1M]
  char* ws = (char*)d_ws;
  bf16* q_cast = (bf16*)ws;
  bf16* k_cast = q_cast + (long)16384 * 1024;
  bf16* S      = q_cast;
  bf16* Qp     = (bf16*)(ws + (size_t)67108864);
  bf16* Kp     = (bf16*)(ws + (size_t)100663296);
  bf16* VT     = (bf16*)(ws + (size_t)134217728);
  bf16* Wqb    = (bf16*)(ws + (size_t)167772160);
  bf16* Wkb    = (bf16*)(ws + (size_t)169869312);

  // merged casts: q+k in one launch, Wq+Wk in another (z selects tensor)
  cast2_f32_bf16<<<dim3(16384, 1, 2), 256, 0, stream>>>(query, q_cast, key, k_cast, 4194304);
  cast2_f32_bf16<<<dim3(1024, 1, 2), 256, 0, stream>>>(Wq, Wqb, Wk, Wkb, 262144);
  transpose_cast<<<dim3(16, 32, 8), 256, 0, stream>>>(value, VT, 2048, 1024);

  // projections, z-fused (z=0: Qp = q_cast@Wq^T+bq; z=1: Kp = k_cast@Wk^T+bk)
  // M=16384, N=1024, K=1024; A stride 16M elems, B stride 1M, C stride 16M.
  gemm_bt<0><<<dim3(4, 64, 2), 512, 0, stream>>>(q_cast, Wqb, bq, bk, Qp, nullptr,
                                                 1024, 1024,
                                                 16777216L, 1048576L, 16777216L);
  // scores: S[b] = (Qp[b] @ Kp[b]^T) / scale   (M=N=2048, K=1024, batched over 8)
  gemm_bt<1><<<dim3(8, 8, 8), 512, 0, stream>>>(Qp, Kp, nullptr, nullptr, S, scale,
                                                2048, 1024,
                                                (long)L * D, (long)L * D, (long)L * L);
  softmax_rows<<<16384, 256, 0, stream>>>(S);
  // out: O[b] = P[b] @ VT[b]^T  (M=2048, N=1024, K=2048, f32 out)
  gemm_bt<2><<<dim3(4, 8, 8), 512, 0, stream>>>(S, VT, nullptr, nullptr, d_out, nullptr,
                                                1024, 2048,
                                                (long)L * L, (long)D * L, (long)L * D);
}

// Round 12
// 278.088 us; speedup vs baseline: 1.0985x; 1.0007x over previous
//
#include <hip/hip_runtime.h>

typedef __bf16 bf16;
typedef __attribute__((ext_vector_type(4))) __bf16 bf16x4;
typedef __attribute__((ext_vector_type(8))) __bf16 bf16x8;
typedef __attribute__((ext_vector_type(4))) float f32x4;

__device__ __forceinline__ void gload_lds16(const void* g, void* l) {
  __builtin_amdgcn_global_load_lds(
      (const __attribute__((address_space(1))) unsigned int*)(unsigned long long)g,
      (__attribute__((address_space(3))) unsigned int*)(unsigned long long)l,
      16, 0, 0);
}

// ------------- fused preprocessing: q cast | k cast | Wq/Wk cast | V transpose -------------
// 1-D grid, 256 threads, role selected by block-id range (uniform per block):
//   [0, 16384)       : query f32->bf16, 4 elems/thread (exact, no tail)
//   [16384, 32768)   : key   f32->bf16
//   [32768, 34816)   : Wq (first 1024) / Wk (next 1024) f32->bf16
//   [34816, 38912)   : V transpose+cast, 512 blocks/batch: x=l&15, y=(l>>4)&31, b=l>>9
// Index math copied verbatim from the three verified standalone kernels.
__global__ void prep(const float* __restrict__ query, bf16* __restrict__ q_cast,
                     const float* __restrict__ key, bf16* __restrict__ k_cast,
                     const float* __restrict__ Wq, bf16* __restrict__ Wqb,
                     const float* __restrict__ Wk, bf16* __restrict__ Wkb,
                     const float* __restrict__ V, bf16* __restrict__ VT) {
  __shared__ bf16 tile[64][65];
  const int bid = blockIdx.x;
  const int t = threadIdx.x;
  if (bid < 34816) {
    const float* in;
    bf16* out;
    long i;
    if (bid < 16384) {
      in = query; out = q_cast; i = (long)bid * 256 + t;
    } else if (bid < 32768) {
      in = key; out = k_cast; i = (long)(bid - 16384) * 256 + t;
    } else {
      const int w = bid - 32768;
      in = (w < 1024) ? Wq : Wk;
      out = (w < 1024) ? Wqb : Wkb;
      i = (long)(w & 1023) * 256 + t;
    }
    float4 v = reinterpret_cast<const float4*>(in)[i];
    bf16x4 o;
    o[0] = (bf16)v.x; o[1] = (bf16)v.y; o[2] = (bf16)v.z; o[3] = (bf16)v.w;
    reinterpret_cast<bf16x4*>(out)[i] = o;
    return;
  }
  // ---- V transpose: V[2048 k][1024 d] -> VT[1024 d][2048 k], batched over 8 ----
  const int l = bid - 34816;
  const int rows = 2048, cols = 1024;
  const int b = l >> 9;
  const float* Vb = V + (long)b * rows * cols;
  bf16* VTb = VT + (long)b * rows * cols;
  const int d0 = (l & 15) * 64;
  const int k0 = ((l >> 4) & 31) * 64;
  const int r = t >> 4;
  const int c4 = (t & 15) * 4;
#pragma unroll
  for (int p = 0; p < 4; ++p) {
    float4 v = *reinterpret_cast<const float4*>(&Vb[(long)(k0 + p * 16 + r) * cols + d0 + c4]);
    tile[p * 16 + r][c4 + 0] = (bf16)v.x;
    tile[p * 16 + r][c4 + 1] = (bf16)v.y;
    tile[p * 16 + r][c4 + 2] = (bf16)v.z;
    tile[p * 16 + r][c4 + 3] = (bf16)v.w;
  }
  __syncthreads();
#pragma unroll
  for (int p = 0; p < 4; ++p) {
    const int dd = p * 16 + r;
    bf16x4 o;
    o[0] = tile[c4 + 0][dd];
    o[1] = tile[c4 + 1][dd];
    o[2] = tile[c4 + 2][dd];
    o[3] = tile[c4 + 3][dd];
    *reinterpret_cast<bf16x4*>(&VTb[(long)(d0 + dd) * rows + k0 + c4]) = o;
  }
}

// ---------------- in-place row softmax, row length 2048, bf16 ----------------
__global__ void softmax_rows(bf16* __restrict__ S) {
  const long row = blockIdx.x;
  bf16* p = S + row * 2048;
  const int t = threadIdx.x;
  const int wid = t >> 6;
  const int lane = t & 63;
  bf16x8 v = *reinterpret_cast<bf16x8*>(p + t * 8);
  float f[8];
  float m = -3.0e38f;
#pragma unroll
  for (int j = 0; j < 8; ++j) { f[j] = (float)v[j]; m = fmaxf(m, f[j]); }
#pragma unroll
  for (int off = 32; off >= 1; off >>= 1) m = fmaxf(m, __shfl_xor(m, off));
  __shared__ float redm[4], reds[4];
  if (lane == 0) redm[wid] = m;
  __syncthreads();
  m = fmaxf(fmaxf(redm[0], redm[1]), fmaxf(redm[2], redm[3]));
  float s = 0.f;
#pragma unroll
  for (int j = 0; j < 8; ++j) { f[j] = __expf(f[j] - m); s += f[j]; }
#pragma unroll
  for (int off = 32; off >= 1; off >>= 1) s += __shfl_xor(s, off);
  if (lane == 0) reds[wid] = s;
  __syncthreads();
  s = reds[0] + reds[1] + reds[2] + reds[3];
  const float inv = 1.0f / s;
  bf16x8 o;
#pragma unroll
  for (int j = 0; j < 8; ++j) o[j] = (bf16)(f[j] * inv);
  *reinterpret_cast<bf16x8*>(p + t * 8) = o;
}

// ---------------- B^T GEMM, 256x256 tile, BK=64, 8-phase (R2 core, best measured) ------
// 512 threads = 8 waves (2 M x 4 N), each wave owns a 128x64 output sub-tile.
// LDS [buf2][op2][half2][128][64] bf16 = 128 KiB, XOR chunk swizzle kc^(row&7)
// (measured: 0 bank conflicts, 97-99 us per 68.7-GFLOP launch; 278.3 us total @R11).
// MODE 0: bf16 out + bias (bz selects bias0/bias1); MODE 1: bf16 * (1/scale); MODE 2: f32.

#define BARRIER __builtin_amdgcn_s_barrier()
#define LGKM0                                              \
  do {                                                     \
    asm volatile("s_waitcnt lgkmcnt(0)" ::: "memory");     \
    __builtin_amdgcn_sched_barrier(0);                     \
  } while (0)
#define VM0                                                \
  do {                                                     \
    asm volatile("s_waitcnt vmcnt(0)" ::: "memory");       \
    __builtin_amdgcn_sched_barrier(0);                     \
  } while (0)

#define STAGE_A(buf, ko)                                        \
  {                                                             \
    bf16* l_ = ldsd + (buf) * 32768;                            \
    const bf16* g_ = gA + (ko);                                 \
    gload_lds16(g_, l_);                                        \
    gload_lds16(g_ + rK64, l_ + 4096);                          \
    gload_lds16(g_ + rK128, l_ + 8192);                         \
    gload_lds16(g_ + rK128 + rK64, l_ + 12288);                 \
  }
#define STAGE_B(buf, ko)                                        \
  {                                                             \
    bf16* l_ = ldsd + (buf) * 32768 + 16384;                    \
    const bf16* g_ = gB + (ko);                                 \
    gload_lds16(g_, l_);                                        \
    gload_lds16(g_ + rK64, l_ + 4096);                          \
    gload_lds16(g_ + rK128, l_ + 8192);                         \
    gload_lds16(g_ + rK128 + rK64, l_ + 12288);                 \
  }

#define LOADA(buf, mq)                                                        \
  {                                                                           \
    const bf16* p_ = aBase + (buf) * 32768 + (mq) * 4096;                     \
    _Pragma("unroll") for (int m_ = 0; m_ < 4; ++m_) {                        \
      a[m_][0] = *reinterpret_cast<const bf16x8*>(p_ + m_ * 1024 + pk0);      \
      a[m_][1] = *reinterpret_cast<const bf16x8*>(p_ + m_ * 1024 + pk1);      \
    }                                                                         \
  }
#define LOADB(buf, nq)                                                        \
  {                                                                           \
    const bf16* p_ = bBase + (buf) * 32768 + (nq) * 2048;                     \
    _Pragma("unroll") for (int n_ = 0; n_ < 2; ++n_) {                        \
      b[(nq) * 2 + n_][0] = *reinterpret_cast<const bf16x8*>(p_ + n_ * 1024 + pk0); \
      b[(nq) * 2 + n_][1] = *reinterpret_cast<const bf16x8*>(p_ + n_ * 1024 + pk1); \
    }                                                                         \
  }

#define MFMAQ(mq, nq)                                                         \
  _Pragma("unroll") for (int m_ = 0; m_ < 4; ++m_)                            \
  _Pragma("unroll") for (int n_ = 0; n_ < 2; ++n_)                            \
  _Pragma("unroll") for (int ks_ = 0; ks_ < 2; ++ks_)                         \
      acc[(mq) * 4 + m_][(nq) * 2 + n_] =                                     \
          __builtin_amdgcn_mfma_f32_16x16x32_bf16(                            \
              a[m_][ks_], b[(nq) * 2 + n_][ks_],                              \
              acc[(mq) * 4 + m_][(nq) * 2 + n_], 0, 0, 0);

template <int MODE>
__global__ __launch_bounds__(512, 2)
void gemm_bt(const bf16* __restrict__ A, const bf16* __restrict__ Bm,
             const float* __restrict__ bias0, const float* __restrict__ bias1,
             void* __restrict__ Cvoid, const int* __restrict__ scale_ptr,
             int N, int K, long sA, long sB, long sC) {
  __shared__ bf16 lds[2][2][2][128][64];  // [buf][opA/B][half][row][64k] = 128 KiB
  const int t = threadIdx.x;
  const int lane = t & 63;
  const int wid = t >> 6;   // 0..7
  const int wm = wid >> 2;  // 0..1
  const int wn = wid & 3;   // 0..3

  // XCD-aware bijective swizzle (all grids here have nwg % 8 == 0)
  const int gx = gridDim.x, gy = gridDim.y;
  const int nwg = gx * gy * gridDim.z;
  int id = blockIdx.x + gx * (blockIdx.y + gy * blockIdx.z);
  {
    const int cpx = nwg >> 3;
    id = (id & 7) * cpx + (id >> 3);
  }
  const int bx = id % gx;
  const int by = (id / gx) % gy;
  const int bz = id / (gx * gy);

  const bf16* Ab = A + (long)bz * sA;
  const bf16* Bb = Bm + (long)bz * sB;
  const int tile_m = by * 256;
  const int tile_n = bx * 256;

  // staging: half-tile = [128][64] = 1024 x 16B chunks; thread t covers chunk t
  // (row=t>>3, kc=t&7) and chunk t+512 (row+64). Source pre-swizzled: global
  // chunk = kc ^ (row&7). Dest linear: elem = chunk*8 (wave-uniform + lane*16B).
  const int srow = t >> 3;
  const int skc = t & 7;
  const int soff = ((skc ^ (srow & 7)) << 3);
  const bf16* gA = Ab + (long)(tile_m + srow) * K + soff;
  const bf16* gB = Bb + (long)(tile_n + srow) * K + soff;
  const long rK64 = (long)K << 6;    // +64 rows
  const long rK128 = (long)K << 7;   // +128 rows (half stride)
  bf16* const ldsd = &lds[0][0][0][0][0] + wid * 512;

  // fragment reads: lane reads row frow=lane&15 of its half, logical k-chunk
  // ks*4+(lane>>4); physical chunk = logical ^ (row&7) = logical ^ (lane&7).
  const int frow = lane & 15;
  const int pk0 = (((lane >> 4) ^ (lane & 7))) << 3;
  const int pk1 = (((4 | (lane >> 4)) ^ (lane & 7))) << 3;
  const bf16* aBase = &lds[0][0][wm][frow][0];
  const bf16* bBase = &lds[0][1][wn >> 1][(wn & 1) * 64 + frow][0];

  bf16x8 a[4][2], b[4][2];
  f32x4 acc[8][4] = {};

  // prologue: stage tile 0 fully, drain once, sync
  STAGE_A(0, 0)
  STAGE_B(0, 0)
  VM0;
  BARRIER;

  const int NK = K >> 6;
  int c = 0;
  for (int kt = 0; kt < NK - 1; ++kt, c ^= 1) {
    const long ko = (long)(kt + 1) << 6;
    // P0: quadrant (0,0); prefetch A of kt+1
    LOADA(c, 0)
    LOADB(c, 0)
    STAGE_A(c ^ 1, ko)
    BARRIER;
    LGKM0;
    __builtin_amdgcn_s_setprio(1);
    MFMAQ(0, 0)
    __builtin_amdgcn_s_setprio(0);
    BARRIER;
    // P1: quadrant (0,1); prefetch B of kt+1
    LOADB(c, 1)
    STAGE_B(c ^ 1, ko)
    BARRIER;
    LGKM0;
    __builtin_amdgcn_s_setprio(1);
    MFMAQ(0, 1)
    __builtin_amdgcn_s_setprio(0);
    BARRIER;
    // P2: quadrant (1,0)
    LOADA(c, 1)
    BARRIER;
    LGKM0;
    __builtin_amdgcn_s_setprio(1);
    MFMAQ(1, 0)
    __builtin_amdgcn_s_setprio(0);
    BARRIER;
    // P3: boundary — drain kt+1's loads (issued 2-3 phases ago), sync, last quadrant
    VM0;
    BARRIER;
    __builtin_amdgcn_s_setprio(1);
    MFMAQ(1, 1)
    __builtin_amdgcn_s_setprio(0);
  }
  // peeled last tile: pure compute from buf c (no staging, compiler-managed waits)
  LOADA(c, 0)
  LOADB(c, 0)
  LOADB(c, 1)
  MFMAQ(0, 0)
  MFMAQ(0, 1)
  LOADA(c, 1)
  MFMAQ(1, 0)
  MFMAQ(1, 1)

  float scl = 1.0f;
  if (MODE == 1) {
    const int iv = scale_ptr[0];
    const float fv = __int_as_float(iv);
    const float sv = (iv > 0 && iv < (1 << 20)) ? (float)iv : fv;
    scl = 1.0f / sv;
  }
  // C/D layout (verified m89/m91): col=lane&15, row=(lane>>4)*4+reg
  const int rb = tile_m + wm * 128 + ((lane >> 4) << 2);
  const int cb = tile_n + wn * 64 + (lane & 15);
  if (MODE == 2) {
    float* C = reinterpret_cast<float*>(Cvoid) + (long)bz * sC;
#pragma unroll
    for (int mf = 0; mf < 8; ++mf)
#pragma unroll
      for (int nf = 0; nf < 4; ++nf)
#pragma unroll
        for (int r = 0; r < 4; ++r)
          C[(long)(rb + mf * 16 + r) * N + (cb + nf * 16)] = acc[mf][nf][r];
  } else {
    bf16* C = reinterpret_cast<bf16*>(Cvoid) + (long)bz * sC;
    const float* bias = (MODE == 0) ? (bz ? bias1 : bias0) : nullptr;
#pragma unroll
    for (int nf = 0; nf < 4; ++nf) {
      const int col = cb + nf * 16;
      const float bv = (MODE == 0) ? bias[col] : 0.0f;
#pragma unroll
      for (int mf = 0; mf < 8; ++mf)
#pragma unroll
        for (int r = 0; r < 4; ++r)
          C[(long)(rb + mf * 16 + r) * N + col] = (bf16)(acc[mf][nf][r] * scl + bv);
    }
  }
}

extern "C" void kernel_launch(void* const* d_in, const int* in_sizes, int n_in,
                              void* d_out, int out_size, void* d_ws, size_t ws_size,
                              hipStream_t stream) {
  (void)in_sizes; (void)n_in; (void)out_size; (void)ws_size;
  const float* query = (const float*)d_in[0];
  const float* key   = (const float*)d_in[1];
  const float* value = (const float*)d_in[2];
  const float* Wq    = (const float*)d_in[3];
  const float* bq    = (const float*)d_in[4];
  const float* Wk    = (const float*)d_in[5];
  const float* bk    = (const float*)d_in[6];
  const int*   scale = (const int*)d_in[7];

  const int L = 2048, D = 1024;
  // ws layout (bytes):
  //   [0,   64M): q_cast(32M) + k_cast(32M) [contiguous, stride 16M elems],
  //               later reused as S/P (8*2048*2048 bf16 = 64M exactly)
  //   [64M, 96M): Qp   [96M,128M): Kp [contiguous, stride 16M elems]
  //   [128M,160M): VT   [160M,162M): Wq_b  [162M,164M): Wk_b [contiguous, stride 1M]
  char* ws = (char*)d_ws;
  bf16* q_cast = (bf16*)ws;
  bf16* k_cast = q_cast + (long)16384 * 1024;
  bf16* S      = q_cast;
  bf16* Qp     = (bf16*)(ws + (size_t)67108864);
  bf16* Kp     = (bf16*)(ws + (size_t)100663296);
  bf16* VT     = (bf16*)(ws + (size_t)134217728);
  bf16* Wqb    = (bf16*)(ws + (size_t)167772160);
  bf16* Wkb    = (bf16*)(ws + (size_t)169869312);

  // fused preprocessing: all casts + V transpose in ONE launch
  prep<<<38912, 256, 0, stream>>>(query, q_cast, key, k_cast,
                                  Wq, Wqb, Wk, Wkb, value, VT);

  // projections, z-fused (z=0: Qp = q_cast@Wq^T+bq; z=1: Kp = k_cast@Wk^T+bk)
  // M=16384, N=1024, K=1024; A stride 16M elems, B stride 1M, C stride 16M.
  gemm_bt<0><<<dim3(4, 64, 2), 512, 0, stream>>>(q_cast, Wqb, bq, bk, Qp, nullptr,
                                                 1024, 1024,
                                                 16777216L, 1048576L, 16777216L);
  // scores: S[b] = (Qp[b] @ Kp[b]^T) / scale   (M=N=2048, K=1024, batched over 8)
  gemm_bt<1><<<dim3(8, 8, 8), 512, 0, stream>>>(Qp, Kp, nullptr, nullptr, S, scale,
                                                2048, 1024,
                                                (long)L * D, (long)L * D, (long)L * L);
  softmax_rows<<<16384, 256, 0, stream>>>(S);
  // out: O[b] = P[b] @ VT[b]^T  (M=2048, N=1024, K=2048, f32 out)
  gemm_bt<2><<<dim3(4, 8, 8), 512, 0, stream>>>(S, VT, nullptr, nullptr, d_out, nullptr,
                                                1024, 2048,
                                                (long)L * L, (long)D * L, (long)L * D);
}

// Round 13
// 271.781 us; speedup vs baseline: 1.1240x; 1.0232x over previous
//
#include <hip/hip_runtime.h>

typedef __bf16 bf16;
typedef __attribute__((ext_vector_type(4))) __bf16 bf16x4;
typedef __attribute__((ext_vector_type(8))) __bf16 bf16x8;
typedef __attribute__((ext_vector_type(4))) float f32x4;

__device__ __forceinline__ void gload_lds16(const void* g, void* l) {
  __builtin_amdgcn_global_load_lds(
      (const __attribute__((address_space(1))) unsigned int*)(unsigned long long)g,
      (__attribute__((address_space(3))) unsigned int*)(unsigned long long)l,
      16, 0, 0);
}

// ------------- fused preprocessing: q cast | k cast | Wq/Wk cast | V transpose -------------
__global__ void prep(const float* __restrict__ query, bf16* __restrict__ q_cast,
                     const float* __restrict__ key, bf16* __restrict__ k_cast,
                     const float* __restrict__ Wq, bf16* __restrict__ Wqb,
                     const float* __restrict__ Wk, bf16* __restrict__ Wkb,
                     const float* __restrict__ V, bf16* __restrict__ VT) {
  __shared__ bf16 tile[64][65];
  const int bid = blockIdx.x;
  const int t = threadIdx.x;
  if (bid < 34816) {
    const float* in;
    bf16* out;
    long i;
    if (bid < 16384) {
      in = query; out = q_cast; i = (long)bid * 256 + t;
    } else if (bid < 32768) {
      in = key; out = k_cast; i = (long)(bid - 16384) * 256 + t;
    } else {
      const int w = bid - 32768;
      in = (w < 1024) ? Wq : Wk;
      out = (w < 1024) ? Wqb : Wkb;
      i = (long)(w & 1023) * 256 + t;
    }
    float4 v = reinterpret_cast<const float4*>(in)[i];
    bf16x4 o;
    o[0] = (bf16)v.x; o[1] = (bf16)v.y; o[2] = (bf16)v.z; o[3] = (bf16)v.w;
    reinterpret_cast<bf16x4*>(out)[i] = o;
    return;
  }
  // ---- V transpose: V[2048 k][1024 d] -> VT[1024 d][2048 k], batched over 8 ----
  const int l = bid - 34816;
  const int rows = 2048, cols = 1024;
  const int b = l >> 9;
  const float* Vb = V + (long)b * rows * cols;
  bf16* VTb = VT + (long)b * rows * cols;
  const int d0 = (l & 15) * 64;
  const int k0 = ((l >> 4) & 31) * 64;
  const int r = t >> 4;
  const int c4 = (t & 15) * 4;
#pragma unroll
  for (int p = 0; p < 4; ++p) {
    float4 v = *reinterpret_cast<const float4*>(&Vb[(long)(k0 + p * 16 + r) * cols + d0 + c4]);
    tile[p * 16 + r][c4 + 0] = (bf16)v.x;
    tile[p * 16 + r][c4 + 1] = (bf16)v.y;
    tile[p * 16 + r][c4 + 2] = (bf16)v.z;
    tile[p * 16 + r][c4 + 3] = (bf16)v.w;
  }
  __syncthreads();
#pragma unroll
  for (int p = 0; p < 4; ++p) {
    const int dd = p * 16 + r;
    bf16x4 o;
    o[0] = tile[c4 + 0][dd];
    o[1] = tile[c4 + 1][dd];
    o[2] = tile[c4 + 2][dd];
    o[3] = tile[c4 + 3][dd];
    *reinterpret_cast<bf16x4*>(&VTb[(long)(d0 + dd) * rows + k0 + c4]) = o;
  }
}

// ---------------- in-place row softmax, row length 2048, bf16 ----------------
__global__ void softmax_rows(bf16* __restrict__ S) {
  const long row = blockIdx.x;
  bf16* p = S + row * 2048;
  const int t = threadIdx.x;
  const int wid = t >> 6;
  const int lane = t & 63;
  bf16x8 v = *reinterpret_cast<bf16x8*>(p + t * 8);
  float f[8];
  float m = -3.0e38f;
#pragma unroll
  for (int j = 0; j < 8; ++j) { f[j] = (float)v[j]; m = fmaxf(m, f[j]); }
#pragma unroll
  for (int off = 32; off >= 1; off >>= 1) m = fmaxf(m, __shfl_xor(m, off));
  __shared__ float redm[4], reds[4];
  if (lane == 0) redm[wid] = m;
  __syncthreads();
  m = fmaxf(fmaxf(redm[0], redm[1]), fmaxf(redm[2], redm[3]));
  float s = 0.f;
#pragma unroll
  for (int j = 0; j < 8; ++j) { f[j] = __expf(f[j] - m); s += f[j]; }
#pragma unroll
  for (int off = 32; off >= 1; off >>= 1) s += __shfl_xor(s, off);
  if (lane == 0) reds[wid] = s;
  __syncthreads();
  s = reds[0] + reds[1] + reds[2] + reds[3];
  const float inv = 1.0f / s;
  bf16x8 o;
#pragma unroll
  for (int j = 0; j < 8; ++j) o[j] = (bf16)(f[j] * inv);
  *reinterpret_cast<bf16x8*>(p + t * 8) = o;
}

// ---------------- B^T GEMM, 256x256 tile, BK=64, 8-phase (R2 core, best measured) ------
// 512 threads = 8 waves (2 M x 4 N), each wave owns a 128x64 output sub-tile.
// LDS [buf2][op2][half2][128][64] bf16 = 128 KiB, XOR chunk swizzle kc^(row&7)
// (measured: 0 bank conflicts, 97-99 us per 68.7-GFLOP launch; 278.1 us total @R12).
// NEW @R13: bf16 epilogue (MODE 0/1) coalesced through LDS -- the direct per-lane
// bf16 store pattern emits 32 B row-fragments (half an HBM line) -> measured 2x
// WRITE_SIZE amplification (126-132 MB vs 64 ideal). Reuse the (dead) 128 KB staging
// LDS as a 256x256 bf16 tile; waves deposit scaled/biased acc, then 512 threads
// stream full 512 B rows out with bf16x8 stores (fully coalesced).
// MODE 0: bf16 out + bias (bz selects bias0/bias1); MODE 1: bf16 * (1/scale); MODE 2: f32.

#define BARRIER __builtin_amdgcn_s_barrier()
#define LGKM0                                              \
  do {                                                     \
    asm volatile("s_waitcnt lgkmcnt(0)" ::: "memory");     \
    __builtin_amdgcn_sched_barrier(0);                     \
  } while (0)
#define VM0                                                \
  do {                                                     \
    asm volatile("s_waitcnt vmcnt(0)" ::: "memory");       \
    __builtin_amdgcn_sched_barrier(0);                     \
  } while (0)

#define STAGE_A(buf, ko)                                        \
  {                                                             \
    bf16* l_ = ldsd + (buf) * 32768;                            \
    const bf16* g_ = gA + (ko);                                 \
    gload_lds16(g_, l_);                                        \
    gload_lds16(g_ + rK64, l_ + 4096);                          \
    gload_lds16(g_ + rK128, l_ + 8192);                         \
    gload_lds16(g_ + rK128 + rK64, l_ + 12288);                 \
  }
#define STAGE_B(buf, ko)                                        \
  {                                                             \
    bf16* l_ = ldsd + (buf) * 32768 + 16384;                    \
    const bf16* g_ = gB + (ko);                                 \
    gload_lds16(g_, l_);                                        \
    gload_lds16(g_ + rK64, l_ + 4096);                          \
    gload_lds16(g_ + rK128, l_ + 8192);                         \
    gload_lds16(g_ + rK128 + rK64, l_ + 12288);                 \
  }

#define LOADA(buf, mq)                                                        \
  {                                                                           \
    const bf16* p_ = aBase + (buf) * 32768 + (mq) * 4096;                     \
    _Pragma("unroll") for (int m_ = 0; m_ < 4; ++m_) {                        \
      a[m_][0] = *reinterpret_cast<const bf16x8*>(p_ + m_ * 1024 + pk0);      \
      a[m_][1] = *reinterpret_cast<const bf16x8*>(p_ + m_ * 1024 + pk1);      \
    }                                                                         \
  }
#define LOADB(buf, nq)                                                        \
  {                                                                           \
    const bf16* p_ = bBase + (buf) * 32768 + (nq) * 2048;                     \
    _Pragma("unroll") for (int n_ = 0; n_ < 2; ++n_) {                        \
      b[(nq) * 2 + n_][0] = *reinterpret_cast<const bf16x8*>(p_ + n_ * 1024 + pk0); \
      b[(nq) * 2 + n_][1] = *reinterpret_cast<const bf16x8*>(p_ + n_ * 1024 + pk1); \
    }                                                                         \
  }

#define MFMAQ(mq, nq)                                                         \
  _Pragma("unroll") for (int m_ = 0; m_ < 4; ++m_)                            \
  _Pragma("unroll") for (int n_ = 0; n_ < 2; ++n_)                            \
  _Pragma("unroll") for (int ks_ = 0; ks_ < 2; ++ks_)                         \
      acc[(mq) * 4 + m_][(nq) * 2 + n_] =                                     \
          __builtin_amdgcn_mfma_f32_16x16x32_bf16(                            \
              a[m_][ks_], b[(nq) * 2 + n_][ks_],                              \
              acc[(mq) * 4 + m_][(nq) * 2 + n_], 0, 0, 0);

template <int MODE>
__global__ __launch_bounds__(512, 2)
void gemm_bt(const bf16* __restrict__ A, const bf16* __restrict__ Bm,
             const float* __restrict__ bias0, const float* __restrict__ bias1,
             void* __restrict__ Cvoid, const int* __restrict__ scale_ptr,
             int N, int K, long sA, long sB, long sC) {
  __shared__ bf16 lds[2][2][2][128][64];  // [buf][opA/B][half][row][64k] = 128 KiB
  const int t = threadIdx.x;
  const int lane = t & 63;
  const int wid = t >> 6;   // 0..7
  const int wm = wid >> 2;  // 0..1
  const int wn = wid & 3;   // 0..3

  // XCD-aware bijective swizzle (all grids here have nwg % 8 == 0)
  const int gx = gridDim.x, gy = gridDim.y;
  const int nwg = gx * gy * gridDim.z;
  int id = blockIdx.x + gx * (blockIdx.y + gy * blockIdx.z);
  {
    const int cpx = nwg >> 3;
    id = (id & 7) * cpx + (id >> 3);
  }
  const int bx = id % gx;
  const int by = (id / gx) % gy;
  const int bz = id / (gx * gy);

  const bf16* Ab = A + (long)bz * sA;
  const bf16* Bb = Bm + (long)bz * sB;
  const int tile_m = by * 256;
  const int tile_n = bx * 256;

  // staging: half-tile = [128][64] = 1024 x 16B chunks; thread t covers chunk t
  // (row=t>>3, kc=t&7) and chunk t+512 (row+64). Source pre-swizzled: global
  // chunk = kc ^ (row&7). Dest linear: elem = chunk*8 (wave-uniform + lane*16B).
  const int srow = t >> 3;
  const int skc = t & 7;
  const int soff = ((skc ^ (srow & 7)) << 3);
  const bf16* gA = Ab + (long)(tile_m + srow) * K + soff;
  const bf16* gB = Bb + (long)(tile_n + srow) * K + soff;
  const long rK64 = (long)K << 6;    // +64 rows
  const long rK128 = (long)K << 7;   // +128 rows (half stride)
  bf16* const ldsd = &lds[0][0][0][0][0] + wid * 512;

  // fragment reads: lane reads row frow=lane&15 of its half, logical k-chunk
  // ks*4+(lane>>4); physical chunk = logical ^ (row&7) = logical ^ (lane&7).
  const int frow = lane & 15;
  const int pk0 = (((lane >> 4) ^ (lane & 7))) << 3;
  const int pk1 = (((4 | (lane >> 4)) ^ (lane & 7))) << 3;
  const bf16* aBase = &lds[0][0][wm][frow][0];
  const bf16* bBase = &lds[0][1][wn >> 1][(wn & 1) * 64 + frow][0];

  bf16x8 a[4][2], b[4][2];
  f32x4 acc[8][4] = {};

  // prologue: stage tile 0 fully, drain once, sync
  STAGE_A(0, 0)
  STAGE_B(0, 0)
  VM0;
  BARRIER;

  const int NK = K >> 6;
  int c = 0;
  for (int kt = 0; kt < NK - 1; ++kt, c ^= 1) {
    const long ko = (long)(kt + 1) << 6;
    // P0: quadrant (0,0); prefetch A of kt+1
    LOADA(c, 0)
    LOADB(c, 0)
    STAGE_A(c ^ 1, ko)
    BARRIER;
    LGKM0;
    __builtin_amdgcn_s_setprio(1);
    MFMAQ(0, 0)
    __builtin_amdgcn_s_setprio(0);
    BARRIER;
    // P1: quadrant (0,1); prefetch B of kt+1
    LOADB(c, 1)
    STAGE_B(c ^ 1, ko)
    BARRIER;
    LGKM0;
    __builtin_amdgcn_s_setprio(1);
    MFMAQ(0, 1)
    __builtin_amdgcn_s_setprio(0);
    BARRIER;
    // P2: quadrant (1,0)
    LOADA(c, 1)
    BARRIER;
    LGKM0;
    __builtin_amdgcn_s_setprio(1);
    MFMAQ(1, 0)
    __builtin_amdgcn_s_setprio(0);
    BARRIER;
    // P3: boundary — drain kt+1's loads (issued 2-3 phases ago), sync, last quadrant
    VM0;
    BARRIER;
    __builtin_amdgcn_s_setprio(1);
    MFMAQ(1, 1)
    __builtin_amdgcn_s_setprio(0);
  }
  // peeled last tile: pure compute from buf c (no staging, compiler-managed waits)
  LOADA(c, 0)
  LOADB(c, 0)
  LOADB(c, 1)
  MFMAQ(0, 0)
  MFMAQ(0, 1)
  LOADA(c, 1)
  MFMAQ(1, 0)
  MFMAQ(1, 1)

  float scl = 1.0f;
  if (MODE == 1) {
    const int iv = scale_ptr[0];
    const float fv = __int_as_float(iv);
    const float sv = (iv > 0 && iv < (1 << 20)) ? (float)iv : fv;
    scl = 1.0f / sv;
  }
  // C/D layout (verified m89/m91): col=lane&15, row=(lane>>4)*4+reg
  if (MODE == 2) {
    const int rb = tile_m + wm * 128 + ((lane >> 4) << 2);
    const int cb = tile_n + wn * 64 + (lane & 15);
    float* C = reinterpret_cast<float*>(Cvoid) + (long)bz * sC;
#pragma unroll
    for (int mf = 0; mf < 8; ++mf)
#pragma unroll
      for (int nf = 0; nf < 4; ++nf)
#pragma unroll
        for (int r = 0; r < 4; ++r)
          C[(long)(rb + mf * 16 + r) * N + (cb + nf * 16)] = acc[mf][nf][r];
  } else {
    // coalesced bf16 epilogue through LDS (kills the 2x WRITE amplification)
    __syncthreads();  // all waves done with K-loop LDS reads before reuse
    bf16(*ldsC)[256] = reinterpret_cast<bf16(*)[256]>(&lds[0][0][0][0][0]);
    const float* bias = (MODE == 0) ? (bz ? bias1 : bias0) : nullptr;
    const int lr = (lane >> 4) << 2;  // 0,4,8,12
    const int lc = lane & 15;
#pragma unroll
    for (int nf = 0; nf < 4; ++nf) {
      const int col = wn * 64 + nf * 16 + lc;  // block-local column
      const float bv = (MODE == 0) ? bias[tile_n + col] : 0.0f;
#pragma unroll
      for (int mf = 0; mf < 8; ++mf)
#pragma unroll
        for (int r = 0; r < 4; ++r)
          ldsC[wm * 128 + mf * 16 + lr + r][col] = (bf16)(acc[mf][nf][r] * scl + bv);
    }
    __syncthreads();
    bf16* C = reinterpret_cast<bf16*>(Cvoid) + (long)bz * sC;
    const int rrow = t >> 5;         // 0..15
    const int ce = (t & 31) * 8;     // col elem, 32 threads x 16B = 512B row
#pragma unroll
    for (int pass = 0; pass < 16; ++pass) {
      const int row = pass * 16 + rrow;
      bf16x8 v = *reinterpret_cast<const bf16x8*>(&ldsC[row][ce]);
      *reinterpret_cast<bf16x8*>(&C[(long)(tile_m + row) * N + tile_n + ce]) = v;
    }
  }
}

extern "C" void kernel_launch(void* const* d_in, const int* in_sizes, int n_in,
                              void* d_out, int out_size, void* d_ws, size_t ws_size,
                              hipStream_t stream) {
  (void)in_sizes; (void)n_in; (void)out_size; (void)ws_size;
  const float* query = (const float*)d_in[0];
  const float* key   = (const float*)d_in[1];
  const float* value = (const float*)d_in[2];
  const float* Wq    = (const float*)d_in[3];
  const float* bq    = (const float*)d_in[4];
  const float* Wk    = (const float*)d_in[5];
  const float* bk    = (const float*)d_in[6];
  const int*   scale = (const int*)d_in[7];

  const int L = 2048, D = 1024;
  // ws layout (bytes):
  //   [0,   64M): q_cast(32M) + k_cast(32M) [contiguous, stride 16M elems],
  //               later reused as S/P (8*2048*2048 bf16 = 64M exactly)
  //   [64M, 96M): Qp   [96M,128M): Kp [contiguous, stride 16M elems]
  //   [128M,160M): VT   [160M,162M): Wq_b  [162M,164M): Wk_b [contiguous, stride 1M]
  char* ws = (char*)d_ws;
  bf16* q_cast = (bf16*)ws;
  bf16* k_cast = q_cast + (long)16384 * 1024;
  bf16* S      = q_cast;
  bf16* Qp     = (bf16*)(ws + (size_t)67108864);
  bf16* Kp     = (bf16*)(ws + (size_t)100663296);
  bf16* VT     = (bf16*)(ws + (size_t)134217728);
  bf16* Wqb    = (bf16*)(ws + (size_t)167772160);
  bf16* Wkb    = (bf16*)(ws + (size_t)169869312);

  // fused preprocessing: all casts + V transpose in ONE launch
  prep<<<38912, 256, 0, stream>>>(query, q_cast, key, k_cast,
                                  Wq, Wqb, Wk, Wkb, value, VT);

  // projections, z-fused (z=0: Qp = q_cast@Wq^T+bq; z=1: Kp = k_cast@Wk^T+bk)
  gemm_bt<0><<<dim3(4, 64, 2), 512, 0, stream>>>(q_cast, Wqb, bq, bk, Qp, nullptr,
                                                 1024, 1024,
                                                 16777216L, 1048576L, 16777216L);
  // scores: S[b] = (Qp[b] @ Kp[b]^T) / scale   (M=N=2048, K=1024, batched over 8)
  gemm_bt<1><<<dim3(8, 8, 8), 512, 0, stream>>>(Qp, Kp, nullptr, nullptr, S, scale,
                                                2048, 1024,
                                                (long)L * D, (long)L * D, (long)L * L);
  softmax_rows<<<16384, 256, 0, stream>>>(S);
  // out: O[b] = P[b] @ VT[b]^T  (M=2048, N=1024, K=2048, f32 out)
  gemm_bt<2><<<dim3(4, 8, 8), 512, 0, stream>>>(S, VT, nullptr, nullptr, d_out, nullptr,
                                                1024, 2048,
                                                (long)L * L, (long)D * L, (long)L * D);
}

// Round 14
// 271.668 us; speedup vs baseline: 1.1244x; 1.0004x over previous
//
#include <hip/hip_runtime.h>

typedef __bf16 bf16;
typedef __attribute__((ext_vector_type(4))) __bf16 bf16x4;
typedef __attribute__((ext_vector_type(8))) __bf16 bf16x8;
typedef __attribute__((ext_vector_type(4))) float f32x4;

__device__ __forceinline__ void gload_lds16(const void* g, void* l) {
  __builtin_amdgcn_global_load_lds(
      (const __attribute__((address_space(1))) unsigned int*)(unsigned long long)g,
      (__attribute__((address_space(3))) unsigned int*)(unsigned long long)l,
      16, 0, 0);
}

// ------------- fused preprocessing: q cast | k cast | Wq/Wk cast | V transpose -------------
__global__ void prep(const float* __restrict__ query, bf16* __restrict__ q_cast,
                     const float* __restrict__ key, bf16* __restrict__ k_cast,
                     const float* __restrict__ Wq, bf16* __restrict__ Wqb,
                     const float* __restrict__ Wk, bf16* __restrict__ Wkb,
                     const float* __restrict__ V, bf16* __restrict__ VT) {
  __shared__ bf16 tile[64][65];
  const int bid = blockIdx.x;
  const int t = threadIdx.x;
  if (bid < 34816) {
    const float* in;
    bf16* out;
    long i;
    if (bid < 16384) {
      in = query; out = q_cast; i = (long)bid * 256 + t;
    } else if (bid < 32768) {
      in = key; out = k_cast; i = (long)(bid - 16384) * 256 + t;
    } else {
      const int w = bid - 32768;
      in = (w < 1024) ? Wq : Wk;
      out = (w < 1024) ? Wqb : Wkb;
      i = (long)(w & 1023) * 256 + t;
    }
    float4 v = reinterpret_cast<const float4*>(in)[i];
    bf16x4 o;
    o[0] = (bf16)v.x; o[1] = (bf16)v.y; o[2] = (bf16)v.z; o[3] = (bf16)v.w;
    reinterpret_cast<bf16x4*>(out)[i] = o;
    return;
  }
  // ---- V transpose: V[2048 k][1024 d] -> VT[1024 d][2048 k], batched over 8 ----
  const int l = bid - 34816;
  const int rows = 2048, cols = 1024;
  const int b = l >> 9;
  const float* Vb = V + (long)b * rows * cols;
  bf16* VTb = VT + (long)b * rows * cols;
  const int d0 = (l & 15) * 64;
  const int k0 = ((l >> 4) & 31) * 64;
  const int r = t >> 4;
  const int c4 = (t & 15) * 4;
#pragma unroll
  for (int p = 0; p < 4; ++p) {
    float4 v = *reinterpret_cast<const float4*>(&Vb[(long)(k0 + p * 16 + r) * cols + d0 + c4]);
    tile[p * 16 + r][c4 + 0] = (bf16)v.x;
    tile[p * 16 + r][c4 + 1] = (bf16)v.y;
    tile[p * 16 + r][c4 + 2] = (bf16)v.z;
    tile[p * 16 + r][c4 + 3] = (bf16)v.w;
  }
  __syncthreads();
#pragma unroll
  for (int p = 0; p < 4; ++p) {
    const int dd = p * 16 + r;
    bf16x4 o;
    o[0] = tile[c4 + 0][dd];
    o[1] = tile[c4 + 1][dd];
    o[2] = tile[c4 + 2][dd];
    o[3] = tile[c4 + 3][dd];
    *reinterpret_cast<bf16x4*>(&VTb[(long)(d0 + dd) * rows + k0 + c4]) = o;
  }
}

// ---------------- in-place row softmax, row length 2048, bf16 ----------------
__global__ void softmax_rows(bf16* __restrict__ S) {
  const long row = blockIdx.x;
  bf16* p = S + row * 2048;
  const int t = threadIdx.x;
  const int wid = t >> 6;
  const int lane = t & 63;
  bf16x8 v = *reinterpret_cast<bf16x8*>(p + t * 8);
  float f[8];
  float m = -3.0e38f;
#pragma unroll
  for (int j = 0; j < 8; ++j) { f[j] = (float)v[j]; m = fmaxf(m, f[j]); }
#pragma unroll
  for (int off = 32; off >= 1; off >>= 1) m = fmaxf(m, __shfl_xor(m, off));
  __shared__ float redm[4], reds[4];
  if (lane == 0) redm[wid] = m;
  __syncthreads();
  m = fmaxf(fmaxf(redm[0], redm[1]), fmaxf(redm[2], redm[3]));
  float s = 0.f;
#pragma unroll
  for (int j = 0; j < 8; ++j) { f[j] = __expf(f[j] - m); s += f[j]; }
#pragma unroll
  for (int off = 32; off >= 1; off >>= 1) s += __shfl_xor(s, off);
  if (lane == 0) reds[wid] = s;
  __syncthreads();
  s = reds[0] + reds[1] + reds[2] + reds[3];
  const float inv = 1.0f / s;
  bf16x8 o;
#pragma unroll
  for (int j = 0; j < 8; ++j) o[j] = (bf16)(f[j] * inv);
  *reinterpret_cast<bf16x8*>(p + t * 8) = o;
}

// ---------------- B^T GEMM, 256x256 tile, BK=64, 8-phase (R2 core, best measured) ------
// 512 threads = 8 waves (2 M x 4 N), each wave owns a 128x64 output sub-tile.
// LDS [buf2][op2][half2][128][64] bf16 = 128 KiB, XOR chunk swizzle kc^(row&7)
// (measured: 0 staging conflicts, 87.9-91.8 us per 68.7-GFLOP launch; 271.8 us @R13).
// bf16 epilogue (MODE 0/1) coalesced through LDS (R13: WRITE 132->65.5 MB).
// NEW @R14: epilogue tile XOR chunk swizzle physChunk = (col>>3)^(row&7) -- kills the
// 4-way deposit ds_write conflict (R13: 1.05M cycles); readback swizzle is
// lane-constant since row&7 = rrow&7 (pass stride 16 = 0 mod 8).
// MODE 0: bf16 out + bias (bz selects bias0/bias1); MODE 1: bf16 * (1/scale); MODE 2: f32.

#define BARRIER __builtin_amdgcn_s_barrier()
#define LGKM0                                              \
  do {                                                     \
    asm volatile("s_waitcnt lgkmcnt(0)" ::: "memory");     \
    __builtin_amdgcn_sched_barrier(0);                     \
  } while (0)
#define VM0                                                \
  do {                                                     \
    asm volatile("s_waitcnt vmcnt(0)" ::: "memory");       \
    __builtin_amdgcn_sched_barrier(0);                     \
  } while (0)

#define STAGE_A(buf, ko)                                        \
  {                                                             \
    bf16* l_ = ldsd + (buf) * 32768;                            \
    const bf16* g_ = gA + (ko);                                 \
    gload_lds16(g_, l_);                                        \
    gload_lds16(g_ + rK64, l_ + 4096);                          \
    gload_lds16(g_ + rK128, l_ + 8192);                         \
    gload_lds16(g_ + rK128 + rK64, l_ + 12288);                 \
  }
#define STAGE_B(buf, ko)                                        \
  {                                                             \
    bf16* l_ = ldsd + (buf) * 32768 + 16384;                    \
    const bf16* g_ = gB + (ko);                                 \
    gload_lds16(g_, l_);                                        \
    gload_lds16(g_ + rK64, l_ + 4096);                          \
    gload_lds16(g_ + rK128, l_ + 8192);                         \
    gload_lds16(g_ + rK128 + rK64, l_ + 12288);                 \
  }

#define LOADA(buf, mq)                                                        \
  {                                                                           \
    const bf16* p_ = aBase + (buf) * 32768 + (mq) * 4096;                     \
    _Pragma("unroll") for (int m_ = 0; m_ < 4; ++m_) {                        \
      a[m_][0] = *reinterpret_cast<const bf16x8*>(p_ + m_ * 1024 + pk0);      \
      a[m_][1] = *reinterpret_cast<const bf16x8*>(p_ + m_ * 1024 + pk1);      \
    }                                                                         \
  }
#define LOADB(buf, nq)                                                        \
  {                                                                           \
    const bf16* p_ = bBase + (buf) * 32768 + (nq) * 2048;                     \
    _Pragma("unroll") for (int n_ = 0; n_ < 2; ++n_) {                        \
      b[(nq) * 2 + n_][0] = *reinterpret_cast<const bf16x8*>(p_ + n_ * 1024 + pk0); \
      b[(nq) * 2 + n_][1] = *reinterpret_cast<const bf16x8*>(p_ + n_ * 1024 + pk1); \
    }                                                                         \
  }

#define MFMAQ(mq, nq)                                                         \
  _Pragma("unroll") for (int m_ = 0; m_ < 4; ++m_)                            \
  _Pragma("unroll") for (int n_ = 0; n_ < 2; ++n_)                            \
  _Pragma("unroll") for (int ks_ = 0; ks_ < 2; ++ks_)                         \
      acc[(mq) * 4 + m_][(nq) * 2 + n_] =                                     \
          __builtin_amdgcn_mfma_f32_16x16x32_bf16(                            \
              a[m_][ks_], b[(nq) * 2 + n_][ks_],                              \
              acc[(mq) * 4 + m_][(nq) * 2 + n_], 0, 0, 0);

template <int MODE>
__global__ __launch_bounds__(512, 2)
void gemm_bt(const bf16* __restrict__ A, const bf16* __restrict__ Bm,
             const float* __restrict__ bias0, const float* __restrict__ bias1,
             void* __restrict__ Cvoid, const int* __restrict__ scale_ptr,
             int N, int K, long sA, long sB, long sC) {
  __shared__ bf16 lds[2][2][2][128][64];  // [buf][opA/B][half][row][64k] = 128 KiB
  const int t = threadIdx.x;
  const int lane = t & 63;
  const int wid = t >> 6;   // 0..7
  const int wm = wid >> 2;  // 0..1
  const int wn = wid & 3;   // 0..3

  // XCD-aware bijective swizzle (all grids here have nwg % 8 == 0)
  const int gx = gridDim.x, gy = gridDim.y;
  const int nwg = gx * gy * gridDim.z;
  int id = blockIdx.x + gx * (blockIdx.y + gy * blockIdx.z);
  {
    const int cpx = nwg >> 3;
    id = (id & 7) * cpx + (id >> 3);
  }
  const int bx = id % gx;
  const int by = (id / gx) % gy;
  const int bz = id / (gx * gy);

  const bf16* Ab = A + (long)bz * sA;
  const bf16* Bb = Bm + (long)bz * sB;
  const int tile_m = by * 256;
  const int tile_n = bx * 256;

  // staging: half-tile = [128][64] = 1024 x 16B chunks; thread t covers chunk t
  // (row=t>>3, kc=t&7) and chunk t+512 (row+64). Source pre-swizzled: global
  // chunk = kc ^ (row&7). Dest linear: elem = chunk*8 (wave-uniform + lane*16B).
  const int srow = t >> 3;
  const int skc = t & 7;
  const int soff = ((skc ^ (srow & 7)) << 3);
  const bf16* gA = Ab + (long)(tile_m + srow) * K + soff;
  const bf16* gB = Bb + (long)(tile_n + srow) * K + soff;
  const long rK64 = (long)K << 6;    // +64 rows
  const long rK128 = (long)K << 7;   // +128 rows (half stride)
  bf16* const ldsd = &lds[0][0][0][0][0] + wid * 512;

  // fragment reads: lane reads row frow=lane&15 of its half, logical k-chunk
  // ks*4+(lane>>4); physical chunk = logical ^ (row&7) = logical ^ (lane&7).
  const int frow = lane & 15;
  const int pk0 = (((lane >> 4) ^ (lane & 7))) << 3;
  const int pk1 = (((4 | (lane >> 4)) ^ (lane & 7))) << 3;
  const bf16* aBase = &lds[0][0][wm][frow][0];
  const bf16* bBase = &lds[0][1][wn >> 1][(wn & 1) * 64 + frow][0];

  bf16x8 a[4][2], b[4][2];
  f32x4 acc[8][4] = {};

  // prologue: stage tile 0 fully, drain once, sync
  STAGE_A(0, 0)
  STAGE_B(0, 0)
  VM0;
  BARRIER;

  const int NK = K >> 6;
  int c = 0;
  for (int kt = 0; kt < NK - 1; ++kt, c ^= 1) {
    const long ko = (long)(kt + 1) << 6;
    // P0: quadrant (0,0); prefetch A of kt+1
    LOADA(c, 0)
    LOADB(c, 0)
    STAGE_A(c ^ 1, ko)
    BARRIER;
    LGKM0;
    __builtin_amdgcn_s_setprio(1);
    MFMAQ(0, 0)
    __builtin_amdgcn_s_setprio(0);
    BARRIER;
    // P1: quadrant (0,1); prefetch B of kt+1
    LOADB(c, 1)
    STAGE_B(c ^ 1, ko)
    BARRIER;
    LGKM0;
    __builtin_amdgcn_s_setprio(1);
    MFMAQ(0, 1)
    __builtin_amdgcn_s_setprio(0);
    BARRIER;
    // P2: quadrant (1,0)
    LOADA(c, 1)
    BARRIER;
    LGKM0;
    __builtin_amdgcn_s_setprio(1);
    MFMAQ(1, 0)
    __builtin_amdgcn_s_setprio(0);
    BARRIER;
    // P3: boundary — drain kt+1's loads (issued 2-3 phases ago), sync, last quadrant
    VM0;
    BARRIER;
    __builtin_amdgcn_s_setprio(1);
    MFMAQ(1, 1)
    __builtin_amdgcn_s_setprio(0);
  }
  // peeled last tile: pure compute from buf c (no staging, compiler-managed waits)
  LOADA(c, 0)
  LOADB(c, 0)
  LOADB(c, 1)
  MFMAQ(0, 0)
  MFMAQ(0, 1)
  LOADA(c, 1)
  MFMAQ(1, 0)
  MFMAQ(1, 1)

  float scl = 1.0f;
  if (MODE == 1) {
    const int iv = scale_ptr[0];
    const float fv = __int_as_float(iv);
    const float sv = (iv > 0 && iv < (1 << 20)) ? (float)iv : fv;
    scl = 1.0f / sv;
  }
  // C/D layout (verified m89/m91): col=lane&15, row=(lane>>4)*4+reg
  if (MODE == 2) {
    const int rb = tile_m + wm * 128 + ((lane >> 4) << 2);
    const int cb = tile_n + wn * 64 + (lane & 15);
    float* C = reinterpret_cast<float*>(Cvoid) + (long)bz * sC;
#pragma unroll
    for (int mf = 0; mf < 8; ++mf)
#pragma unroll
      for (int nf = 0; nf < 4; ++nf)
#pragma unroll
        for (int r = 0; r < 4; ++r)
          C[(long)(rb + mf * 16 + r) * N + (cb + nf * 16)] = acc[mf][nf][r];
  } else {
    // coalesced bf16 epilogue through LDS; physChunk = (col>>3) ^ (row&7) kills the
    // 4-way deposit conflict while keeping readback chunks contiguous.
    __syncthreads();  // all waves done with K-loop LDS reads before reuse
    bf16* const ldsCf = &lds[0][0][0][0][0];
    const float* bias = (MODE == 0) ? (bz ? bias1 : bias0) : nullptr;
    const int lr = (lane >> 4) << 2;  // 0,4,8,12
    const int g4 = lr & 7;            // 0 or 4 == lr mod 8
    const int lc = lane & 15;
#pragma unroll
    for (int nf = 0; nf < 4; ++nf) {
      const int col = wn * 64 + nf * 16 + lc;  // block-local column
      const int cch = col >> 3;
      const int c7 = col & 7;
      const float bv = (MODE == 0) ? bias[tile_n + col] : 0.0f;
#pragma unroll
      for (int mf = 0; mf < 8; ++mf)
#pragma unroll
        for (int r = 0; r < 4; ++r) {
          const int row = wm * 128 + mf * 16 + lr + r;
          const int s = g4 + r;  // == row & 7
          ldsCf[row * 256 + ((cch ^ s) << 3) + c7] = (bf16)(acc[mf][nf][r] * scl + bv);
        }
    }
    __syncthreads();
    bf16* C = reinterpret_cast<bf16*>(Cvoid) + (long)bz * sC;
    const int rrow = t >> 5;                    // 0..15
    const int cc = t & 31;                      // logical 16B chunk
    const int ccs = (cc ^ (rrow & 7)) << 3;     // swizzled elem offset (lane-constant)
    const int ce = cc * 8;                      // logical col for global store
#pragma unroll
    for (int pass = 0; pass < 16; ++pass) {
      const int row = pass * 16 + rrow;         // row&7 == rrow&7 (16 % 8 == 0)
      bf16x8 v = *reinterpret_cast<const bf16x8*>(ldsCf + row * 256 + ccs);
      *reinterpret_cast<bf16x8*>(&C[(long)(tile_m + row) * N + tile_n + ce]) = v;
    }
  }
}

extern "C" void kernel_launch(void* const* d_in, const int* in_sizes, int n_in,
                              void* d_out, int out_size, void* d_ws, size_t ws_size,
                              hipStream_t stream) {
  (void)in_sizes; (void)n_in; (void)out_size; (void)ws_size;
  const float* query = (const float*)d_in[0];
  const float* key   = (const float*)d_in[1];
  const float* value = (const float*)d_in[2];
  const float* Wq    = (const float*)d_in[3];
  const float* bq    = (const float*)d_in[4];
  const float* Wk    = (const float*)d_in[5];
  const float* bk    = (const float*)d_in[6];
  const int*   scale = (const int*)d_in[7];

  const int L = 2048, D = 1024;
  // ws layout (bytes):
  //   [0,   64M): q_cast(32M) + k_cast(32M) [contiguous, stride 16M elems],
  //               later reused as S/P (8*2048*2048 bf16 = 64M exactly)
  //   [64M, 96M): Qp   [96M,128M): Kp [contiguous, stride 16M elems]
  //   [128M,160M): VT   [160M,162M): Wq_b  [162M,164M): Wk_b [contiguous, stride 1M]
  char* ws = (char*)d_ws;
  bf16* q_cast = (bf16*)ws;
  bf16* k_cast = q_cast + (long)16384 * 1024;
  bf16* S      = q_cast;
  bf16* Qp     = (bf16*)(ws + (size_t)67108864);
  bf16* Kp     = (bf16*)(ws + (size_t)100663296);
  bf16* VT     = (bf16*)(ws + (size_t)134217728);
  bf16* Wqb    = (bf16*)(ws + (size_t)167772160);
  bf16* Wkb    = (bf16*)(ws + (size_t)169869312);

  // fused preprocessing: all casts + V transpose in ONE launch
  prep<<<38912, 256, 0, stream>>>(query, q_cast, key, k_cast,
                                  Wq, Wqb, Wk, Wkb, value, VT);

  // projections, z-fused (z=0: Qp = q_cast@Wq^T+bq; z=1: Kp = k_cast@Wk^T+bk)
  gemm_bt<0><<<dim3(4, 64, 2), 512, 0, stream>>>(q_cast, Wqb, bq, bk, Qp, nullptr,
                                                 1024, 1024,
                                                 16777216L, 1048576L, 16777216L);
  // scores: S[b] = (Qp[b] @ Kp[b]^T) / scale   (M=N=2048, K=1024, batched over 8)
  gemm_bt<1><<<dim3(8, 8, 8), 512, 0, stream>>>(Qp, Kp, nullptr, nullptr, S, scale,
                                                2048, 1024,
                                                (long)L * D, (long)L * D, (long)L * L);
  softmax_rows<<<16384, 256, 0, stream>>>(S);
  // out: O[b] = P[b] @ VT[b]^T  (M=2048, N=1024, K=2048, f32 out)
  gemm_bt<2><<<dim3(4, 8, 8), 512, 0, stream>>>(S, VT, nullptr, nullptr, d_out, nullptr,
                                                1024, 2048,
                                                (long)L * L, (long)D * L, (long)L * D);
}